// Round 14
// baseline (813.696 us; speedup 1.0000x reference)
//
#include <hip/hip_runtime.h>
#include <stdint.h>

#define D 512

typedef _Float16 f16;
typedef f16 f16x8 __attribute__((ext_vector_type(8)));
typedef f16 h2 __attribute__((ext_vector_type(2)));
typedef float f32x4 __attribute__((ext_vector_type(4)));
typedef unsigned int u32;
typedef u32 u32x4 __attribute__((ext_vector_type(4)));

static __device__ __forceinline__ u32 bcu(h2 h) { return __builtin_bit_cast(u32, h); }
static __device__ __forceinline__ h2 pkrtz(float a, float b) {
  return __builtin_bit_cast(h2, __builtin_amdgcn_cvt_pkrtz(a, b));
}
static __device__ __forceinline__ f16x8 frag4(u32 w0, u32 w1, u32 w2, u32 w3) {
  u32x4 u = {w0, w1, w2, w3};
  return __builtin_bit_cast(f16x8, u);
}
static __device__ __forceinline__ float fastrcp(float x) {
#if __has_builtin(__builtin_amdgcn_rcpf)
  return __builtin_amdgcn_rcpf(x);
#else
  return 1.0f / x;
#endif
}

// lhi-repack (verified R5-R12): C-layout tile pair -> A-frag (k=m, m 17..31 = 0).
static __device__ __forceinline__ f16x8 repack_frag(float c0, float c1, float c2, float c3,
                                                    float v16, int l15, int lhi) {
  u32 t0a = bcu(pkrtz(c0, c1)), t0b = bcu(pkrtz(c2, c3));
  u32 t1a = bcu(pkrtz(v16, 0.f));
  int srcA = (((lhi * 2) & 3) << 4) | l15;
  int srcB = (((lhi * 2 + 1) & 3) << 4) | l15;
  u32 a0 = (u32)__shfl((int)t0a, srcA);
  u32 a1 = (u32)__shfl((int)t0b, srcA);
  u32 a2 = (u32)__shfl((int)t1a, srcA);
  u32 b0 = (u32)__shfl((int)t0a, srcB);
  u32 b1 = (u32)__shfl((int)t0b, srcB);
  u32 b2 = (u32)__shfl((int)t1a, srcB);
  bool lo = lhi < 2;
  return frag4(lo ? a0 : a2, lo ? a1 : 0u, lo ? b0 : b2, lo ? b1 : 0u);
}

// ---------------- prep_q: blocks 0..255 = Wcat/bcat prep; 256..335 = qproj ----------------
__global__ __launch_bounds__(256) void prep_q_k(
    const float* __restrict__ xf, const float* __restrict__ tn_g,
    const float* __restrict__ tn_b, const float* __restrict__ Wq,
    const float* __restrict__ bq, const float* __restrict__ Wk,
    const float* __restrict__ bk, const float* __restrict__ Wv,
    const float* __restrict__ bv, f16* __restrict__ Wcat,
    float* __restrict__ bcat, f16* __restrict__ q16h) {
  __shared__ __align__(16) unsigned char lds[16384];
  const int bid = blockIdx.x, tid = threadIdx.x;
  const int wv = tid >> 6, lane = tid & 63;
  if (bid < 256) {
    int row = bid * 4 + wv;
    int h = row >> 7, kvs = (row >> 6) & 1, d = row & 63;
    int srow = h * 64 + d;
    const float* src = (kvs ? Wv : Wk) + (size_t)srow * D;
    f32x4 a = *(const f32x4*)(src + lane * 8);
    f32x4 c = *(const f32x4*)(src + lane * 8 + 4);
    uint4 u;
    u.x = bcu(pkrtz(a[0], a[1]));
    u.y = bcu(pkrtz(a[2], a[3]));
    u.z = bcu(pkrtz(c[0], c[1]));
    u.w = bcu(pkrtz(c[2], c[3]));
    *reinterpret_cast<uint4*>(Wcat + (size_t)row * D + lane * 8) = u;
    if (lane == 0) bcat[row] = (kvs ? bv : bk)[srow];
    return;
  }
  const int bid2 = bid - 256;
  const int bs = bid2 & 15, n0 = (bid2 >> 4) * 16;
  const int l15 = lane & 15, lhi = lane >> 4;

  for (int rr = wv; rr < 16; rr += 4) {
    int srcn = n0 + rr;
    if (srcn > 76) srcn = 76;
    const f32x4* xr = (const f32x4*)(xf + ((size_t)(bs * 77 + srcn)) * D);
    f32x4 va = xr[lane * 2], vb = xr[lane * 2 + 1];
    float s = va[0] + va[1] + va[2] + va[3] + vb[0] + vb[1] + vb[2] + vb[3];
    float sq = va[0] * va[0] + va[1] * va[1] + va[2] * va[2] + va[3] * va[3] +
               vb[0] * vb[0] + vb[1] * vb[1] + vb[2] * vb[2] + vb[3] * vb[3];
#pragma unroll
    for (int off = 32; off; off >>= 1) {
      s += __shfl_xor(s, off);
      sq += __shfl_xor(sq, off);
    }
    float mu = s * (1.0f / 512.0f);
    float var = sq * (1.0f / 512.0f) - mu * mu;
    float rstd = rsqrtf(var + 1e-5f);
    f32x4 ga = ((const f32x4*)tn_g)[lane * 2], gb = ((const f32x4*)tn_g)[lane * 2 + 1];
    f32x4 ba = ((const f32x4*)tn_b)[lane * 2], bb = ((const f32x4*)tn_b)[lane * 2 + 1];
    uint4 u;
    u.x = bcu(pkrtz((va[0] - mu) * rstd * ga[0] + ba[0], (va[1] - mu) * rstd * ga[1] + ba[1]));
    u.y = bcu(pkrtz((va[2] - mu) * rstd * ga[2] + ba[2], (va[3] - mu) * rstd * ga[3] + ba[3]));
    u.z = bcu(pkrtz((vb[0] - mu) * rstd * gb[0] + bb[0], (vb[1] - mu) * rstd * gb[1] + bb[1]));
    u.w = bcu(pkrtz((vb[2] - mu) * rstd * gb[2] + bb[2], (vb[3] - mu) * rstd * gb[3] + bb[3]));
    *reinterpret_cast<uint4*>(lds + rr * 1024 + ((lane * 16) ^ ((rr & 7) << 4))) = u;
  }
  __syncthreads();

  f32x4 acc[8];
#pragma unroll
  for (int nt = 0; nt < 8; ++nt) {
    float bias = bq[wv * 128 + nt * 16 + l15];
    acc[nt] = (f32x4){bias, bias, bias, bias};
  }
#pragma unroll 4
  for (int ks = 0; ks < 16; ++ks) {
    f16x8 af = *(const f16x8*)(lds + l15 * 1024 + ((ks * 64 + lhi * 16) ^ ((l15 & 7) << 4)));
#pragma unroll
    for (int nt = 0; nt < 8; ++nt) {
      const float* wr = Wq + (size_t)(wv * 128 + nt * 16 + l15) * D + ks * 32 + lhi * 8;
      f32x4 wa = *(const f32x4*)wr, wb = *(const f32x4*)(wr + 4);
      f16x8 bf = frag4(bcu(pkrtz(wa[0], wa[1])), bcu(pkrtz(wa[2], wa[3])),
                       bcu(pkrtz(wb[0], wb[1])), bcu(pkrtz(wb[2], wb[3])));
      acc[nt] = __builtin_amdgcn_mfma_f32_16x16x32_f16(af, bf, acc[nt], 0, 0, 0);
    }
  }
#pragma unroll
  for (int nt = 0; nt < 8; ++nt) {
    int col = wv * 128 + nt * 16 + l15;
    int h = col >> 6, d = col & 63;
    f16* base = q16h + ((size_t)(h * 16 + bs) * 77) * 64;
#pragma unroll
    for (int r = 0; r < 4; ++r) {
      int n = n0 + lhi * 4 + r;
      if (n < 77) base[n * 64 + d] = (f16)acc[nt][r];
    }
  }
}

// ---------------- fused (R14 = R13 + 64B zeroed LDS slack after VT) ----------------
// grid 3888, 256 threads (4 waves), 1 batch/block. Per hp: wave wv projects cols
// [hp*256+wv*64,+64) (head hhw=wv>>1, K/V isv=wv&1), rows 0..16 (tile0 + row16 bcast).
// KS/VT double-buffered by hp&1; ONE barrier per hp. attn: combo=wv>>1, half=wv&1.
// LDS: xn 17408 | KS 2x2x2448=9792 | VT 2x2x3072=12288 | slack 64 -> 39552 B
// => 4 blocks/CU. The slack absorbs vf's lhi=3 16B row-overrun at the region end.
#define XN_OFF 0
#define KS_OFF 17408
#define VT_OFF 27200
#define LDS_TOTAL 39552

__global__ __launch_bounds__(256, 4) void fused_k(
    const float* __restrict__ x, const float* __restrict__ n_g,
    const float* __restrict__ n_b, const f16* __restrict__ Wcat,
    const float* __restrict__ bcat, const f16* __restrict__ q16h,
    float* __restrict__ out) {
  __shared__ __align__(16) unsigned char lds[LDS_TOTAL];
  const int b = blockIdx.x, bs = b & 15;
  const int tid = threadIdx.x, wv = tid >> 6, lane = tid & 63;
  const int l15 = lane & 15, lhi = lane >> 4;

  // zero VT (both buffers) + 64B slack: PV k in [17,24) and the overrun bytes read 0
  {
    uint4 z;
    z.x = z.y = z.z = z.w = 0u;
    for (int i = tid; i < 772; i += 256)
      *reinterpret_cast<uint4*>(lds + VT_OFF + i * 16) = z;
  }

  // Phase 1: LayerNorm -> xn f16 rows 0..16 (swizzled)
  for (int rr = wv; rr < 17; rr += 4) {
    const f32x4* xr = (const f32x4*)(x + ((size_t)(b * 17 + rr)) * D);
    f32x4 va = xr[lane * 2], vb = xr[lane * 2 + 1];
    float s = va[0] + va[1] + va[2] + va[3] + vb[0] + vb[1] + vb[2] + vb[3];
    float sq = va[0] * va[0] + va[1] * va[1] + va[2] * va[2] + va[3] * va[3] +
               vb[0] * vb[0] + vb[1] * vb[1] + vb[2] * vb[2] + vb[3] * vb[3];
#pragma unroll
    for (int off = 32; off; off >>= 1) {
      s += __shfl_xor(s, off);
      sq += __shfl_xor(sq, off);
    }
    float mu = s * (1.0f / 512.0f);
    float var = sq * (1.0f / 512.0f) - mu * mu;
    float rstd = rsqrtf(var + 1e-5f);
    f32x4 ga = ((const f32x4*)n_g)[lane * 2], gb = ((const f32x4*)n_g)[lane * 2 + 1];
    f32x4 ba = ((const f32x4*)n_b)[lane * 2], bb = ((const f32x4*)n_b)[lane * 2 + 1];
    uint4 u;
    u.x = bcu(pkrtz((va[0] - mu) * rstd * ga[0] + ba[0], (va[1] - mu) * rstd * ga[1] + ba[1]));
    u.y = bcu(pkrtz((va[2] - mu) * rstd * ga[2] + ba[2], (va[3] - mu) * rstd * ga[3] + ba[3]));
    u.z = bcu(pkrtz((vb[0] - mu) * rstd * gb[0] + bb[0], (vb[1] - mu) * rstd * gb[1] + bb[1]));
    u.w = bcu(pkrtz((vb[2] - mu) * rstd * gb[2] + bb[2], (vb[3] - mu) * rstd * gb[3] + bb[3]));
    *reinterpret_cast<uint4*>(lds + XN_OFF + rr * 1024 + ((lane * 16) ^ ((rr & 7) << 4))) = u;
  }
  __syncthreads();

  const int hhw = wv >> 1, isv = wv & 1;  // projection role
  const int combo = wv >> 1;              // attention head within pair
  const int half = wv & 1;                // n-tile subset
  const int ntlo = half * 3, ntcnt = 3 - half;
  const float C2 = 0.18033688011112042f;  // log2(e)/8

  for (int hp = 0; hp < 4; ++hp) {
    const int buf = hp & 1;

    // ---- projection: cols [hp*256 + wv*64, +64), rows 0..16 ----
    f32x4 acc0[4], acc1[4];
#pragma unroll
    for (int nt = 0; nt < 4; ++nt) {
      float bias = bcat[hp * 256 + wv * 64 + nt * 16 + l15];
      acc0[nt] = (f32x4){bias, bias, bias, bias};
      acc1[nt] = acc0[nt];
    }
    const f16* wbase = Wcat + (size_t)(hp * 256 + wv * 64 + l15) * D;
    f16x8 bf[2][4];
#pragma unroll
    for (int p = 0; p < 2; ++p)
#pragma unroll
      for (int nt = 0; nt < 4; ++nt)
        bf[p][nt] = *(const f16x8*)(wbase + (size_t)nt * 16 * D + p * 32 + lhi * 8);
#pragma unroll
    for (int ks = 0; ks < 16; ++ks) {
      const int cur = ks & 1;
      f16x8 af0 = *(const f16x8*)(lds + XN_OFF + l15 * 1024 +
                                  ((ks * 64 + lhi * 16) ^ ((l15 & 7) << 4)));
      f16x8 af1 = *(const f16x8*)(lds + XN_OFF + 16 * 1024 + ks * 64 + lhi * 16);
#pragma unroll
      for (int nt = 0; nt < 4; ++nt) {
        acc0[nt] = __builtin_amdgcn_mfma_f32_16x16x32_f16(af0, bf[cur][nt], acc0[nt], 0, 0, 0);
        acc1[nt] = __builtin_amdgcn_mfma_f32_16x16x32_f16(af1, bf[cur][nt], acc1[nt], 0, 0, 0);
      }
      if (ks < 14) {
#pragma unroll
        for (int nt = 0; nt < 4; ++nt)
          bf[cur][nt] = *(const f16x8*)(wbase + (size_t)nt * 16 * D + (ks + 2) * 32 + lhi * 8);
      }
    }
    // ---- store K/V tiles into buffer `buf` ----
    if (isv) {
      unsigned char* vbase = lds + VT_OFF + buf * 6144 + hhw * 3072;
#pragma unroll
      for (int nt = 0; nt < 4; ++nt) {
        int d = nt * 16 + l15;
        *(u32*)(vbase + d * 48 + (lhi * 4) * 2) = bcu(pkrtz(acc0[nt][0], acc0[nt][1]));
        *(u32*)(vbase + d * 48 + (lhi * 4 + 2) * 2) = bcu(pkrtz(acc0[nt][2], acc0[nt][3]));
        if (lhi == 0) *(f16*)(vbase + d * 48 + 16 * 2) = (f16)acc1[nt][0];
      }
    } else {
      unsigned char* kbase = lds + KS_OFF + buf * 4896 + hhw * 2448;
#pragma unroll
      for (int nt = 0; nt < 4; ++nt) {
        int d = nt * 16 + l15;
#pragma unroll
        for (int r = 0; r < 4; ++r)
          *(f16*)(kbase + (lhi * 4 + r) * 144 + d * 2) = (f16)acc0[nt][r];
        if (lhi == 0) *(f16*)(kbase + 16 * 144 + d * 2) = (f16)acc1[nt][0];
      }
    }
    __syncthreads();

    // ---- attention: head = hp*2 + combo, n-tiles in subset ----
    const int head = hp * 2 + combo;
    const unsigned char* ksb = lds + KS_OFF + buf * 4896 + combo * 2448;
    const unsigned char* vtb = lds + VT_OFF + buf * 6144 + combo * 3072;
    f16x8 kf0[2], kf1[2], vf[4];
#pragma unroll
    for (int c = 0; c < 2; ++c) {
      kf0[c] = *(const f16x8*)(ksb + l15 * 144 + c * 64 + lhi * 16);
      kf1[c] = *(const f16x8*)(ksb + 16 * 144 + c * 64 + lhi * 16);
    }
#pragma unroll
    for (int dt = 0; dt < 4; ++dt)
      vf[dt] = *(const f16x8*)(vtb + (dt * 16 + l15) * 48 + lhi * 16);

    const f16* qb = q16h + ((size_t)(head * 16 + bs) * 77) * 64;
    float* ob = out + (size_t)b * 77 * 512 + head * 64;
#pragma unroll
    for (int t = 0; t < 3; ++t) {
      if (t < ntcnt) {
        int nt = ntlo + t;
        int nq = nt * 16 + l15;
        if (nq > 76) nq = 76;
        f16x8 qf0 = *(const f16x8*)(qb + nq * 64 + lhi * 8);
        f16x8 qf1 = *(const f16x8*)(qb + nq * 64 + 32 + lhi * 8);
        f32x4 z = {0.f, 0.f, 0.f, 0.f};
        f32x4 s0 = z, s1 = z;
        s0 = __builtin_amdgcn_mfma_f32_16x16x32_f16(kf0[0], qf0, s0, 0, 0, 0);
        s0 = __builtin_amdgcn_mfma_f32_16x16x32_f16(kf0[1], qf1, s0, 0, 0, 0);
        s1 = __builtin_amdgcn_mfma_f32_16x16x32_f16(kf1[0], qf0, s1, 0, 0, 0);
        s1 = __builtin_amdgcn_mfma_f32_16x16x32_f16(kf1[1], qf1, s1, 0, 0, 0);
        float mx = fmaxf(fmaxf(s0[0], s0[1]), fmaxf(s0[2], s0[3]));
        mx = fmaxf(mx, __shfl_xor(mx, 16));
        mx = fmaxf(mx, __shfl_xor(mx, 32));
        mx = fmaxf(mx, s1[0]);
        float e0[4];
#pragma unroll
        for (int r = 0; r < 4; ++r) e0[r] = exp2f((s0[r] - mx) * C2);
        float e1 = exp2f((s1[0] - mx) * C2);
        float sm = e0[0] + e0[1] + e0[2] + e0[3];
        sm += __shfl_xor(sm, 16);
        sm += __shfl_xor(sm, 32);
        sm += e1;
        float inv = fastrcp(sm);
#pragma unroll
        for (int r = 0; r < 4; ++r) e0[r] *= inv;
        e1 *= inv;
        f16x8 pfrag =
            repack_frag(e0[0], e0[1], e0[2], e0[3], (lhi == 0) ? e1 : 0.f, l15, lhi);
#pragma unroll
        for (int dt = 0; dt < 4; ++dt) {
          f32x4 o = {0.f, 0.f, 0.f, 0.f};
          o = __builtin_amdgcn_mfma_f32_16x16x32_f16(pfrag, vf[dt], o, 0, 0, 0);
#pragma unroll
          for (int r = 0; r < 4; ++r) {
            int n = nt * 16 + lhi * 4 + r;
            if (n < 77) ob[(size_t)n * 512 + dt * 16 + l15] = o[r];
          }
        }
      }
    }
  }
}

extern "C" void kernel_launch(void* const* d_in, const int* in_sizes, int n_in,
                              void* d_out, int out_size, void* d_ws, size_t ws_size,
                              hipStream_t stream) {
  const float* xf = (const float*)d_in[0];
  const float* x = (const float*)d_in[1];
  const float* tn_g = (const float*)d_in[2];
  const float* tn_b = (const float*)d_in[3];
  const float* n_g = (const float*)d_in[4];
  const float* n_b = (const float*)d_in[5];
  const float* Wq = (const float*)d_in[6];
  const float* bq = (const float*)d_in[7];
  const float* Wk = (const float*)d_in[8];
  const float* bk = (const float*)d_in[9];
  const float* Wv = (const float*)d_in[10];
  const float* bv = (const float*)d_in[11];
  float* out = (float*)d_out;

  char* ws = (char*)d_ws;
  f16* q16h = (f16*)ws;                      // 8*16*77*64*2 = 1,261,568 B (+1024 pad)
  f16* Wcat = (f16*)(ws + 1262592);          // 1024*512*2   = 1,048,576 B
  float* bcat = (float*)(ws + 2311168);      // 1024*4       = 4,096 B

  prep_q_k<<<336, 256, 0, stream>>>(xf, tn_g, tn_b, Wq, bq, Wk, bk, Wv, bv,
                                    Wcat, bcat, q16h);
  fused_k<<<3888, 256, 0, stream>>>(x, n_g, n_b, Wcat, bcat, q16h, out);
}

// Round 15
// 721.500 us; speedup vs baseline: 1.1278x; 1.1278x over previous
//
#include <hip/hip_runtime.h>
#include <stdint.h>

#define D 512

typedef _Float16 f16;
typedef f16 f16x8 __attribute__((ext_vector_type(8)));
typedef f16 h2 __attribute__((ext_vector_type(2)));
typedef float f32x4 __attribute__((ext_vector_type(4)));
typedef unsigned int u32;
typedef u32 u32x4 __attribute__((ext_vector_type(4)));

static __device__ __forceinline__ u32 bcu(h2 h) { return __builtin_bit_cast(u32, h); }
static __device__ __forceinline__ h2 pkrtz(float a, float b) {
  return __builtin_bit_cast(h2, __builtin_amdgcn_cvt_pkrtz(a, b));
}
static __device__ __forceinline__ f16x8 frag4(u32 w0, u32 w1, u32 w2, u32 w3) {
  u32x4 u = {w0, w1, w2, w3};
  return __builtin_bit_cast(f16x8, u);
}
static __device__ __forceinline__ float fastrcp(float x) {
#if __has_builtin(__builtin_amdgcn_rcpf)
  return __builtin_amdgcn_rcpf(x);
#else
  return 1.0f / x;
#endif
}

// lhi-repack (verified R5-R12): C-layout tile pair -> A-frag (k=m, m 17..31 = 0).
static __device__ __forceinline__ f16x8 repack_frag(float c0, float c1, float c2, float c3,
                                                    float v16, int l15, int lhi) {
  u32 t0a = bcu(pkrtz(c0, c1)), t0b = bcu(pkrtz(c2, c3));
  u32 t1a = bcu(pkrtz(v16, 0.f));
  int srcA = (((lhi * 2) & 3) << 4) | l15;
  int srcB = (((lhi * 2 + 1) & 3) << 4) | l15;
  u32 a0 = (u32)__shfl((int)t0a, srcA);
  u32 a1 = (u32)__shfl((int)t0b, srcA);
  u32 a2 = (u32)__shfl((int)t1a, srcA);
  u32 b0 = (u32)__shfl((int)t0a, srcB);
  u32 b1 = (u32)__shfl((int)t0b, srcB);
  u32 b2 = (u32)__shfl((int)t1a, srcB);
  bool lo = lhi < 2;
  return frag4(lo ? a0 : a2, lo ? a1 : 0u, lo ? b0 : b2, lo ? b1 : 0u);
}

// ---------------- prep_q: blocks 0..255 = Wcat/bcat prep; 256..335 = qproj ----------------
__global__ __launch_bounds__(256) void prep_q_k(
    const float* __restrict__ xf, const float* __restrict__ tn_g,
    const float* __restrict__ tn_b, const float* __restrict__ Wq,
    const float* __restrict__ bq, const float* __restrict__ Wk,
    const float* __restrict__ bk, const float* __restrict__ Wv,
    const float* __restrict__ bv, f16* __restrict__ Wcat,
    float* __restrict__ bcat, f16* __restrict__ q16h) {
  __shared__ __align__(16) unsigned char lds[16384];
  const int bid = blockIdx.x, tid = threadIdx.x;
  const int wv = tid >> 6, lane = tid & 63;
  if (bid < 256) {
    int row = bid * 4 + wv;
    int h = row >> 7, kvs = (row >> 6) & 1, d = row & 63;
    int srow = h * 64 + d;
    const float* src = (kvs ? Wv : Wk) + (size_t)srow * D;
    f32x4 a = *(const f32x4*)(src + lane * 8);
    f32x4 c = *(const f32x4*)(src + lane * 8 + 4);
    uint4 u;
    u.x = bcu(pkrtz(a[0], a[1]));
    u.y = bcu(pkrtz(a[2], a[3]));
    u.z = bcu(pkrtz(c[0], c[1]));
    u.w = bcu(pkrtz(c[2], c[3]));
    *reinterpret_cast<uint4*>(Wcat + (size_t)row * D + lane * 8) = u;
    if (lane == 0) bcat[row] = (kvs ? bv : bk)[srow];
    return;
  }
  const int bid2 = bid - 256;
  const int bs = bid2 & 15, n0 = (bid2 >> 4) * 16;
  const int l15 = lane & 15, lhi = lane >> 4;

  for (int rr = wv; rr < 16; rr += 4) {
    int srcn = n0 + rr;
    if (srcn > 76) srcn = 76;
    const f32x4* xr = (const f32x4*)(xf + ((size_t)(bs * 77 + srcn)) * D);
    f32x4 va = xr[lane * 2], vb = xr[lane * 2 + 1];
    float s = va[0] + va[1] + va[2] + va[3] + vb[0] + vb[1] + vb[2] + vb[3];
    float sq = va[0] * va[0] + va[1] * va[1] + va[2] * va[2] + va[3] * va[3] +
               vb[0] * vb[0] + vb[1] * vb[1] + vb[2] * vb[2] + vb[3] * vb[3];
#pragma unroll
    for (int off = 32; off; off >>= 1) {
      s += __shfl_xor(s, off);
      sq += __shfl_xor(sq, off);
    }
    float mu = s * (1.0f / 512.0f);
    float var = sq * (1.0f / 512.0f) - mu * mu;
    float rstd = rsqrtf(var + 1e-5f);
    f32x4 ga = ((const f32x4*)tn_g)[lane * 2], gb = ((const f32x4*)tn_g)[lane * 2 + 1];
    f32x4 ba = ((const f32x4*)tn_b)[lane * 2], bb = ((const f32x4*)tn_b)[lane * 2 + 1];
    uint4 u;
    u.x = bcu(pkrtz((va[0] - mu) * rstd * ga[0] + ba[0], (va[1] - mu) * rstd * ga[1] + ba[1]));
    u.y = bcu(pkrtz((va[2] - mu) * rstd * ga[2] + ba[2], (va[3] - mu) * rstd * ga[3] + ba[3]));
    u.z = bcu(pkrtz((vb[0] - mu) * rstd * gb[0] + bb[0], (vb[1] - mu) * rstd * gb[1] + bb[1]));
    u.w = bcu(pkrtz((vb[2] - mu) * rstd * gb[2] + bb[2], (vb[3] - mu) * rstd * gb[3] + bb[3]));
    *reinterpret_cast<uint4*>(lds + rr * 1024 + ((lane * 16) ^ ((rr & 7) << 4))) = u;
  }
  __syncthreads();

  f32x4 acc[8];
#pragma unroll
  for (int nt = 0; nt < 8; ++nt) {
    float bias = bq[wv * 128 + nt * 16 + l15];
    acc[nt] = (f32x4){bias, bias, bias, bias};
  }
#pragma unroll 4
  for (int ks = 0; ks < 16; ++ks) {
    f16x8 af = *(const f16x8*)(lds + l15 * 1024 + ((ks * 64 + lhi * 16) ^ ((l15 & 7) << 4)));
#pragma unroll
    for (int nt = 0; nt < 8; ++nt) {
      const float* wr = Wq + (size_t)(wv * 128 + nt * 16 + l15) * D + ks * 32 + lhi * 8;
      f32x4 wa = *(const f32x4*)wr, wb = *(const f32x4*)(wr + 4);
      f16x8 bf = frag4(bcu(pkrtz(wa[0], wa[1])), bcu(pkrtz(wa[2], wa[3])),
                       bcu(pkrtz(wb[0], wb[1])), bcu(pkrtz(wb[2], wb[3])));
      acc[nt] = __builtin_amdgcn_mfma_f32_16x16x32_f16(af, bf, acc[nt], 0, 0, 0);
    }
  }
#pragma unroll
  for (int nt = 0; nt < 8; ++nt) {
    int col = wv * 128 + nt * 16 + l15;
    int h = col >> 6, d = col & 63;
    f16* base = q16h + ((size_t)(h * 16 + bs) * 77) * 64;
#pragma unroll
    for (int r = 0; r < 4; ++r) {
      int n = n0 + lhi * 4 + r;
      if (n < 77) base[n * 64 + d] = (f16)acc[nt][r];
    }
  }
}

// ---------------- fused (R15 = R14 without the VGPR-capping launch_bounds arg) --------
// grid 3888, 256 threads (4 waves), 1 batch/block. Per hp: wave wv projects cols
// [hp*256+wv*64,+64) (head hhw=wv>>1, K/V isv=wv&1), rows 0..16 (tile0 + row16 bcast).
// KS/VT double-buffered by hp&1; ONE barrier per hp. attn: combo=wv>>1, half=wv&1.
// LDS: xn 17408 | KS 2x2x2448=9792 | VT 2x2x3072=12288 | slack 64 -> 39552 B
// => 4 blocks/CU by LDS; natural VGPR (~110) <= 128 keeps 4 waves/SIMD.
#define XN_OFF 0
#define KS_OFF 17408
#define VT_OFF 27200
#define LDS_TOTAL 39552

__global__ __launch_bounds__(256) void fused_k(
    const float* __restrict__ x, const float* __restrict__ n_g,
    const float* __restrict__ n_b, const f16* __restrict__ Wcat,
    const float* __restrict__ bcat, const f16* __restrict__ q16h,
    float* __restrict__ out) {
  __shared__ __align__(16) unsigned char lds[LDS_TOTAL];
  const int b = blockIdx.x, bs = b & 15;
  const int tid = threadIdx.x, wv = tid >> 6, lane = tid & 63;
  const int l15 = lane & 15, lhi = lane >> 4;

  // zero VT (both buffers) + 64B slack: PV k in [17,24) and the overrun bytes read 0
  {
    uint4 z;
    z.x = z.y = z.z = z.w = 0u;
    for (int i = tid; i < 772; i += 256)
      *reinterpret_cast<uint4*>(lds + VT_OFF + i * 16) = z;
  }

  // Phase 1: LayerNorm -> xn f16 rows 0..16 (swizzled)
  for (int rr = wv; rr < 17; rr += 4) {
    const f32x4* xr = (const f32x4*)(x + ((size_t)(b * 17 + rr)) * D);
    f32x4 va = xr[lane * 2], vb = xr[lane * 2 + 1];
    float s = va[0] + va[1] + va[2] + va[3] + vb[0] + vb[1] + vb[2] + vb[3];
    float sq = va[0] * va[0] + va[1] * va[1] + va[2] * va[2] + va[3] * va[3] +
               vb[0] * vb[0] + vb[1] * vb[1] + vb[2] * vb[2] + vb[3] * vb[3];
#pragma unroll
    for (int off = 32; off; off >>= 1) {
      s += __shfl_xor(s, off);
      sq += __shfl_xor(sq, off);
    }
    float mu = s * (1.0f / 512.0f);
    float var = sq * (1.0f / 512.0f) - mu * mu;
    float rstd = rsqrtf(var + 1e-5f);
    f32x4 ga = ((const f32x4*)n_g)[lane * 2], gb = ((const f32x4*)n_g)[lane * 2 + 1];
    f32x4 ba = ((const f32x4*)n_b)[lane * 2], bb = ((const f32x4*)n_b)[lane * 2 + 1];
    uint4 u;
    u.x = bcu(pkrtz((va[0] - mu) * rstd * ga[0] + ba[0], (va[1] - mu) * rstd * ga[1] + ba[1]));
    u.y = bcu(pkrtz((va[2] - mu) * rstd * ga[2] + ba[2], (va[3] - mu) * rstd * ga[3] + ba[3]));
    u.z = bcu(pkrtz((vb[0] - mu) * rstd * gb[0] + bb[0], (vb[1] - mu) * rstd * gb[1] + bb[1]));
    u.w = bcu(pkrtz((vb[2] - mu) * rstd * gb[2] + bb[2], (vb[3] - mu) * rstd * gb[3] + bb[3]));
    *reinterpret_cast<uint4*>(lds + XN_OFF + rr * 1024 + ((lane * 16) ^ ((rr & 7) << 4))) = u;
  }
  __syncthreads();

  const int hhw = wv >> 1, isv = wv & 1;  // projection role
  const int combo = wv >> 1;              // attention head within pair
  const int half = wv & 1;                // n-tile subset
  const int ntlo = half * 3, ntcnt = 3 - half;
  const float C2 = 0.18033688011112042f;  // log2(e)/8

  for (int hp = 0; hp < 4; ++hp) {
    const int buf = hp & 1;

    // ---- projection: cols [hp*256 + wv*64, +64), rows 0..16 ----
    f32x4 acc0[4], acc1[4];
#pragma unroll
    for (int nt = 0; nt < 4; ++nt) {
      float bias = bcat[hp * 256 + wv * 64 + nt * 16 + l15];
      acc0[nt] = (f32x4){bias, bias, bias, bias};
      acc1[nt] = acc0[nt];
    }
    const f16* wbase = Wcat + (size_t)(hp * 256 + wv * 64 + l15) * D;
    f16x8 bf[2][4];
#pragma unroll
    for (int p = 0; p < 2; ++p)
#pragma unroll
      for (int nt = 0; nt < 4; ++nt)
        bf[p][nt] = *(const f16x8*)(wbase + (size_t)nt * 16 * D + p * 32 + lhi * 8);
#pragma unroll
    for (int ks = 0; ks < 16; ++ks) {
      const int cur = ks & 1;
      f16x8 af0 = *(const f16x8*)(lds + XN_OFF + l15 * 1024 +
                                  ((ks * 64 + lhi * 16) ^ ((l15 & 7) << 4)));
      f16x8 af1 = *(const f16x8*)(lds + XN_OFF + 16 * 1024 + ks * 64 + lhi * 16);
#pragma unroll
      for (int nt = 0; nt < 4; ++nt) {
        acc0[nt] = __builtin_amdgcn_mfma_f32_16x16x32_f16(af0, bf[cur][nt], acc0[nt], 0, 0, 0);
        acc1[nt] = __builtin_amdgcn_mfma_f32_16x16x32_f16(af1, bf[cur][nt], acc1[nt], 0, 0, 0);
      }
      if (ks < 14) {
#pragma unroll
        for (int nt = 0; nt < 4; ++nt)
          bf[cur][nt] = *(const f16x8*)(wbase + (size_t)nt * 16 * D + (ks + 2) * 32 + lhi * 8);
      }
    }
    // ---- store K/V tiles into buffer `buf` ----
    if (isv) {
      unsigned char* vbase = lds + VT_OFF + buf * 6144 + hhw * 3072;
#pragma unroll
      for (int nt = 0; nt < 4; ++nt) {
        int d = nt * 16 + l15;
        *(u32*)(vbase + d * 48 + (lhi * 4) * 2) = bcu(pkrtz(acc0[nt][0], acc0[nt][1]));
        *(u32*)(vbase + d * 48 + (lhi * 4 + 2) * 2) = bcu(pkrtz(acc0[nt][2], acc0[nt][3]));
        if (lhi == 0) *(f16*)(vbase + d * 48 + 16 * 2) = (f16)acc1[nt][0];
      }
    } else {
      unsigned char* kbase = lds + KS_OFF + buf * 4896 + hhw * 2448;
#pragma unroll
      for (int nt = 0; nt < 4; ++nt) {
        int d = nt * 16 + l15;
#pragma unroll
        for (int r = 0; r < 4; ++r)
          *(f16*)(kbase + (lhi * 4 + r) * 144 + d * 2) = (f16)acc0[nt][r];
        if (lhi == 0) *(f16*)(kbase + 16 * 144 + d * 2) = (f16)acc1[nt][0];
      }
    }
    __syncthreads();

    // ---- attention: head = hp*2 + combo, n-tiles in subset ----
    const int head = hp * 2 + combo;
    const unsigned char* ksb = lds + KS_OFF + buf * 4896 + combo * 2448;
    const unsigned char* vtb = lds + VT_OFF + buf * 6144 + combo * 3072;
    f16x8 kf0[2], kf1[2], vf[4];
#pragma unroll
    for (int c = 0; c < 2; ++c) {
      kf0[c] = *(const f16x8*)(ksb + l15 * 144 + c * 64 + lhi * 16);
      kf1[c] = *(const f16x8*)(ksb + 16 * 144 + c * 64 + lhi * 16);
    }
#pragma unroll
    for (int dt = 0; dt < 4; ++dt)
      vf[dt] = *(const f16x8*)(vtb + (dt * 16 + l15) * 48 + lhi * 16);

    const f16* qb = q16h + ((size_t)(head * 16 + bs) * 77) * 64;
    float* ob = out + (size_t)b * 77 * 512 + head * 64;
#pragma unroll
    for (int t = 0; t < 3; ++t) {
      if (t < ntcnt) {
        int nt = ntlo + t;
        int nq = nt * 16 + l15;
        if (nq > 76) nq = 76;
        f16x8 qf0 = *(const f16x8*)(qb + nq * 64 + lhi * 8);
        f16x8 qf1 = *(const f16x8*)(qb + nq * 64 + 32 + lhi * 8);
        f32x4 z = {0.f, 0.f, 0.f, 0.f};
        f32x4 s0 = z, s1 = z;
        s0 = __builtin_amdgcn_mfma_f32_16x16x32_f16(kf0[0], qf0, s0, 0, 0, 0);
        s0 = __builtin_amdgcn_mfma_f32_16x16x32_f16(kf0[1], qf1, s0, 0, 0, 0);
        s1 = __builtin_amdgcn_mfma_f32_16x16x32_f16(kf1[0], qf0, s1, 0, 0, 0);
        s1 = __builtin_amdgcn_mfma_f32_16x16x32_f16(kf1[1], qf1, s1, 0, 0, 0);
        float mx = fmaxf(fmaxf(s0[0], s0[1]), fmaxf(s0[2], s0[3]));
        mx = fmaxf(mx, __shfl_xor(mx, 16));
        mx = fmaxf(mx, __shfl_xor(mx, 32));
        mx = fmaxf(mx, s1[0]);
        float e0[4];
#pragma unroll
        for (int r = 0; r < 4; ++r) e0[r] = exp2f((s0[r] - mx) * C2);
        float e1 = exp2f((s1[0] - mx) * C2);
        float sm = e0[0] + e0[1] + e0[2] + e0[3];
        sm += __shfl_xor(sm, 16);
        sm += __shfl_xor(sm, 32);
        sm += e1;
        float inv = fastrcp(sm);
#pragma unroll
        for (int r = 0; r < 4; ++r) e0[r] *= inv;
        e1 *= inv;
        f16x8 pfrag =
            repack_frag(e0[0], e0[1], e0[2], e0[3], (lhi == 0) ? e1 : 0.f, l15, lhi);
#pragma unroll
        for (int dt = 0; dt < 4; ++dt) {
          f32x4 o = {0.f, 0.f, 0.f, 0.f};
          o = __builtin_amdgcn_mfma_f32_16x16x32_f16(pfrag, vf[dt], o, 0, 0, 0);
#pragma unroll
          for (int r = 0; r < 4; ++r) {
            int n = nt * 16 + lhi * 4 + r;
            if (n < 77) ob[(size_t)n * 512 + dt * 16 + l15] = o[r];
          }
        }
      }
    }
  }
}

extern "C" void kernel_launch(void* const* d_in, const int* in_sizes, int n_in,
                              void* d_out, int out_size, void* d_ws, size_t ws_size,
                              hipStream_t stream) {
  const float* xf = (const float*)d_in[0];
  const float* x = (const float*)d_in[1];
  const float* tn_g = (const float*)d_in[2];
  const float* tn_b = (const float*)d_in[3];
  const float* n_g = (const float*)d_in[4];
  const float* n_b = (const float*)d_in[5];
  const float* Wq = (const float*)d_in[6];
  const float* bq = (const float*)d_in[7];
  const float* Wk = (const float*)d_in[8];
  const float* bk = (const float*)d_in[9];
  const float* Wv = (const float*)d_in[10];
  const float* bv = (const float*)d_in[11];
  float* out = (float*)d_out;

  char* ws = (char*)d_ws;
  f16* q16h = (f16*)ws;                      // 8*16*77*64*2 = 1,261,568 B (+1024 pad)
  f16* Wcat = (f16*)(ws + 1262592);          // 1024*512*2   = 1,048,576 B
  float* bcat = (float*)(ws + 2311168);      // 1024*4       = 4,096 B

  prep_q_k<<<336, 256, 0, stream>>>(xf, tn_g, tn_b, Wq, bq, Wk, bk, Wv, bv,
                                    Wcat, bcat, q16h);
  fused_k<<<3888, 256, 0, stream>>>(x, n_g, n_b, Wcat, bcat, q16h, out);
}

// Round 16
// 379.783 us; speedup vs baseline: 2.1425x; 1.8998x over previous
//
#include <hip/hip_runtime.h>
#include <stdint.h>

#define D 512

typedef _Float16 f16;
typedef f16 f16x8 __attribute__((ext_vector_type(8)));
typedef f16 h2 __attribute__((ext_vector_type(2)));
typedef float f32x4 __attribute__((ext_vector_type(4)));
typedef unsigned int u32;
typedef u32 u32x4 __attribute__((ext_vector_type(4)));

static __device__ __forceinline__ u32 bcu(h2 h) { return __builtin_bit_cast(u32, h); }
static __device__ __forceinline__ h2 pkrtz(float a, float b) {
  return __builtin_bit_cast(h2, __builtin_amdgcn_cvt_pkrtz(a, b));
}
static __device__ __forceinline__ f16x8 frag4(u32 w0, u32 w1, u32 w2, u32 w3) {
  u32x4 u = {w0, w1, w2, w3};
  return __builtin_bit_cast(f16x8, u);
}
static __device__ __forceinline__ float fastrcp(float x) {
#if __has_builtin(__builtin_amdgcn_rcpf)
  return __builtin_amdgcn_rcpf(x);
#else
  return 1.0f / x;
#endif
}

// lhi-repack (verified R5-R12): C-layout tile pair -> A-frag (k=m, m 17..31 = 0).
static __device__ __forceinline__ f16x8 repack_frag(float c0, float c1, float c2, float c3,
                                                    float v16, int l15, int lhi) {
  u32 t0a = bcu(pkrtz(c0, c1)), t0b = bcu(pkrtz(c2, c3));
  u32 t1a = bcu(pkrtz(v16, 0.f));
  int srcA = (((lhi * 2) & 3) << 4) | l15;
  int srcB = (((lhi * 2 + 1) & 3) << 4) | l15;
  u32 a0 = (u32)__shfl((int)t0a, srcA);
  u32 a1 = (u32)__shfl((int)t0b, srcA);
  u32 a2 = (u32)__shfl((int)t1a, srcA);
  u32 b0 = (u32)__shfl((int)t0a, srcB);
  u32 b1 = (u32)__shfl((int)t0b, srcB);
  u32 b2 = (u32)__shfl((int)t1a, srcB);
  bool lo = lhi < 2;
  return frag4(lo ? a0 : a2, lo ? a1 : 0u, lo ? b0 : b2, lo ? b1 : 0u);
}

// ---------------- prep_q: blocks 0..255 = Wcat/bcat prep; 256..415 = qproj ----------------
// qproj split over 160 blocks (vs 80): each handles 256 output cols -> shorter tail.
__global__ __launch_bounds__(256) void prep_q_k(
    const float* __restrict__ xf, const float* __restrict__ tn_g,
    const float* __restrict__ tn_b, const float* __restrict__ Wq,
    const float* __restrict__ bq, const float* __restrict__ Wk,
    const float* __restrict__ bk, const float* __restrict__ Wv,
    const float* __restrict__ bv, f16* __restrict__ Wcat,
    float* __restrict__ bcat, f16* __restrict__ q16h) {
  __shared__ __align__(16) unsigned char lds[16384];
  const int bid = blockIdx.x, tid = threadIdx.x;
  const int wv = tid >> 6, lane = tid & 63;
  if (bid < 256) {
    int row = bid * 4 + wv;
    int h = row >> 7, kvs = (row >> 6) & 1, d = row & 63;
    int srow = h * 64 + d;
    const float* src = (kvs ? Wv : Wk) + (size_t)srow * D;
    f32x4 a = *(const f32x4*)(src + lane * 8);
    f32x4 c = *(const f32x4*)(src + lane * 8 + 4);
    uint4 u;
    u.x = bcu(pkrtz(a[0], a[1]));
    u.y = bcu(pkrtz(a[2], a[3]));
    u.z = bcu(pkrtz(c[0], c[1]));
    u.w = bcu(pkrtz(c[2], c[3]));
    *reinterpret_cast<uint4*>(Wcat + (size_t)row * D + lane * 8) = u;
    if (lane == 0) bcat[row] = (kvs ? bv : bk)[srow];
    return;
  }
  // ---- qproj: q16h[h][bs][n][64] = LN(xf) @ Wq^T + bq ----
  const int bid2 = bid - 256;          // 0..159
  const int bs = bid2 & 15;
  const int g = bid2 >> 4;             // 0..9
  const int n0 = (g >> 1) * 16;        // 5 n-tiles x 2 col-halves
  const int ch = g & 1;
  const int l15 = lane & 15, lhi = lane >> 4;

  for (int rr = wv; rr < 16; rr += 4) {
    int srcn = n0 + rr;
    if (srcn > 76) srcn = 76;
    const f32x4* xr = (const f32x4*)(xf + ((size_t)(bs * 77 + srcn)) * D);
    f32x4 va = xr[lane * 2], vb = xr[lane * 2 + 1];
    float s = va[0] + va[1] + va[2] + va[3] + vb[0] + vb[1] + vb[2] + vb[3];
    float sq = va[0] * va[0] + va[1] * va[1] + va[2] * va[2] + va[3] * va[3] +
               vb[0] * vb[0] + vb[1] * vb[1] + vb[2] * vb[2] + vb[3] * vb[3];
#pragma unroll
    for (int off = 32; off; off >>= 1) {
      s += __shfl_xor(s, off);
      sq += __shfl_xor(sq, off);
    }
    float mu = s * (1.0f / 512.0f);
    float var = sq * (1.0f / 512.0f) - mu * mu;
    float rstd = rsqrtf(var + 1e-5f);
    f32x4 ga = ((const f32x4*)tn_g)[lane * 2], gb = ((const f32x4*)tn_g)[lane * 2 + 1];
    f32x4 ba = ((const f32x4*)tn_b)[lane * 2], bb = ((const f32x4*)tn_b)[lane * 2 + 1];
    uint4 u;
    u.x = bcu(pkrtz((va[0] - mu) * rstd * ga[0] + ba[0], (va[1] - mu) * rstd * ga[1] + ba[1]));
    u.y = bcu(pkrtz((va[2] - mu) * rstd * ga[2] + ba[2], (va[3] - mu) * rstd * ga[3] + ba[3]));
    u.z = bcu(pkrtz((vb[0] - mu) * rstd * gb[0] + bb[0], (vb[1] - mu) * rstd * gb[1] + bb[1]));
    u.w = bcu(pkrtz((vb[2] - mu) * rstd * gb[2] + bb[2], (vb[3] - mu) * rstd * gb[3] + bb[3]));
    *reinterpret_cast<uint4*>(lds + rr * 1024 + ((lane * 16) ^ ((rr & 7) << 4))) = u;
  }
  __syncthreads();

  f32x4 acc[4];
#pragma unroll
  for (int nt = 0; nt < 4; ++nt) {
    float bias = bq[ch * 256 + wv * 64 + nt * 16 + l15];
    acc[nt] = (f32x4){bias, bias, bias, bias};
  }
#pragma unroll 4
  for (int ks = 0; ks < 16; ++ks) {
    f16x8 af = *(const f16x8*)(lds + l15 * 1024 + ((ks * 64 + lhi * 16) ^ ((l15 & 7) << 4)));
#pragma unroll
    for (int nt = 0; nt < 4; ++nt) {
      const float* wr = Wq + (size_t)(ch * 256 + wv * 64 + nt * 16 + l15) * D + ks * 32 + lhi * 8;
      f32x4 wa = *(const f32x4*)wr, wb = *(const f32x4*)(wr + 4);
      f16x8 bf = frag4(bcu(pkrtz(wa[0], wa[1])), bcu(pkrtz(wa[2], wa[3])),
                       bcu(pkrtz(wb[0], wb[1])), bcu(pkrtz(wb[2], wb[3])));
      acc[nt] = __builtin_amdgcn_mfma_f32_16x16x32_f16(af, bf, acc[nt], 0, 0, 0);
    }
  }
#pragma unroll
  for (int nt = 0; nt < 4; ++nt) {
    int col = ch * 256 + wv * 64 + nt * 16 + l15;
    int h = col >> 6, d = col & 63;
    f16* base = q16h + ((size_t)(h * 16 + bs) * 77) * 64;
#pragma unroll
    for (int r = 0; r < 4; ++r) {
      int n = n0 + lhi * 4 + r;
      if (n < 77) base[n * 64 + d] = (f16)acc[nt][r];
    }
  }
}

// ---------------- fused (R16 = R10 verbatim — measured best: 386 us) ----------------
// LDS: xn [34][1024B swz] | KS dbuf 2x4x[17][144B] | VT dbuf 2x4x[64][48B].
// Per hp: qf hoist -> proj (3-slot rotating B-prefetch) -> stores -> barrier -> attn.
#define XN_OFF 0
#define KS_OFF 34816
#define VT_OFF 54400
#define LDS_TOTAL 79040

__global__ __launch_bounds__(256, 2) void fused_k(
    const float* __restrict__ x, const float* __restrict__ n_g,
    const float* __restrict__ n_b, const f16* __restrict__ Wcat,
    const float* __restrict__ bcat, const f16* __restrict__ q16h,
    float* __restrict__ out) {
  __shared__ __align__(16) unsigned char lds[LDS_TOTAL];
  const int b0 = blockIdx.x * 2;
  const int tid = threadIdx.x, wv = tid >> 6, lane = tid & 63;
  const int l15 = lane & 15, lhi = lane >> 4;

  // zero VT (both buffers + slack): PV k in [17,24) must read 0
  {
    uint4 z;
    z.x = z.y = z.z = z.w = 0u;
    for (int i = tid; i < 1540; i += 256)
      *reinterpret_cast<uint4*>(lds + VT_OFF + i * 16) = z;
  }

  // Phase 1: LayerNorm -> xn f16 rows 0..33 (swizzled)
  for (int rr = wv; rr < 34; rr += 4) {
    const f32x4* xr = (const f32x4*)(x + ((size_t)(b0 * 17 + rr)) * D);
    f32x4 va = xr[lane * 2], vb = xr[lane * 2 + 1];
    float s = va[0] + va[1] + va[2] + va[3] + vb[0] + vb[1] + vb[2] + vb[3];
    float sq = va[0] * va[0] + va[1] * va[1] + va[2] * va[2] + va[3] * va[3] +
               vb[0] * vb[0] + vb[1] * vb[1] + vb[2] * vb[2] + vb[3] * vb[3];
#pragma unroll
    for (int off = 32; off; off >>= 1) {
      s += __shfl_xor(s, off);
      sq += __shfl_xor(sq, off);
    }
    float mu = s * (1.0f / 512.0f);
    float var = sq * (1.0f / 512.0f) - mu * mu;
    float rstd = rsqrtf(var + 1e-5f);
    f32x4 ga = ((const f32x4*)n_g)[lane * 2], gb = ((const f32x4*)n_g)[lane * 2 + 1];
    f32x4 ba = ((const f32x4*)n_b)[lane * 2], bb = ((const f32x4*)n_b)[lane * 2 + 1];
    uint4 u;
    u.x = bcu(pkrtz((va[0] - mu) * rstd * ga[0] + ba[0], (va[1] - mu) * rstd * ga[1] + ba[1]));
    u.y = bcu(pkrtz((va[2] - mu) * rstd * ga[2] + ba[2], (va[3] - mu) * rstd * ga[3] + ba[3]));
    u.z = bcu(pkrtz((vb[0] - mu) * rstd * gb[0] + bb[0], (vb[1] - mu) * rstd * gb[1] + bb[1]));
    u.w = bcu(pkrtz((vb[2] - mu) * rstd * gb[2] + bb[2], (vb[3] - mu) * rstd * gb[3] + bb[3]));
    *reinterpret_cast<uint4*>(lds + XN_OFF + rr * 1024 + ((lane * 16) ^ ((rr & 7) << 4))) = u;
  }
  __syncthreads();

  const int hhw = wv >> 1, isv = wv & 1;  // projection role (cols)
  const int bb = wv & 1;                  // attention combo = wv
  const int b = b0 + bb, bs = b & 15;
  const float C2 = 0.18033688011112042f;  // log2(e)/8

  for (int hp = 0; hp < 4; ++hp) {
    const int buf = hp & 1;
    const int head_a = hp * 2 + hhw;

    // ---- hoist Q fragments (overlaps projection; verified OK at R8 liveness) ----
    const f16* qb = q16h + ((size_t)(head_a * 16 + bs) * 77) * 64;
    f16x8 qf[5][2];
#pragma unroll
    for (int nt = 0; nt < 5; ++nt) {
      int nq = nt * 16 + l15;
      if (nq > 76) nq = 76;
      qf[nt][0] = *(const f16x8*)(qb + nq * 64 + lhi * 8);
      qf[nt][1] = *(const f16x8*)(qb + nq * 64 + 32 + lhi * 8);
    }

    // ---- cooperative projection: slab cols [hp*256 + wv*64, +64), rows 0..33 ----
    f32x4 acc[3][4];
#pragma unroll
    for (int nt = 0; nt < 4; ++nt) {
      float bias = bcat[hp * 256 + wv * 64 + nt * 16 + l15];
      f32x4 bi = {bias, bias, bias, bias};
#pragma unroll
      for (int mt = 0; mt < 3; ++mt) acc[mt][nt] = bi;
    }
    const f16* wbase = Wcat + (size_t)(hp * 256 + wv * 64 + l15) * D;
    // 3-slot rotating prefetch: slots hold ks, ks+1, ks+2 (~2 iters of flight)
    f16x8 bf[3][4];
#pragma unroll
    for (int p = 0; p < 3; ++p)
#pragma unroll
      for (int nt = 0; nt < 4; ++nt)
        bf[p][nt] = *(const f16x8*)(wbase + (size_t)nt * 16 * D + p * 32 + lhi * 8);
#pragma unroll
    for (int ks = 0; ks < 16; ++ks) {
      const int cur = ks % 3;
#pragma unroll
      for (int mt = 0; mt < 3; ++mt) {
        int arow = mt * 16 + l15;
        f16x8 af = *(const f16x8*)(lds + XN_OFF + arow * 1024 +
                                   ((ks * 64 + lhi * 16) ^ ((arow & 7) << 4)));
#pragma unroll
        for (int nt = 0; nt < 4; ++nt)
          acc[mt][nt] =
              __builtin_amdgcn_mfma_f32_16x16x32_f16(af, bf[cur][nt], acc[mt][nt], 0, 0, 0);
      }
      if (ks < 13) {
#pragma unroll
        for (int nt = 0; nt < 4; ++nt)
          bf[cur][nt] = *(const f16x8*)(wbase + (size_t)nt * 16 * D + (ks + 3) * 32 + lhi * 8);
      }
    }
    // ---- store K/V tiles into double-buffered LDS ----
    if (isv) {
      // VT [combo][d][m]: r-pairs are m-consecutive -> packed u32 stores.
      unsigned char* vbase = lds + VT_OFF + buf * 12288;
#pragma unroll
      for (int mt = 0; mt < 3; ++mt) {
#pragma unroll
        for (int nt = 0; nt < 4; ++nt) {
          int d = nt * 16 + l15;
#pragma unroll
          for (int r = 0; r < 4; r += 2) {
            int mrow = mt * 16 + lhi * 4 + r;  // even
            if (mrow == 16) {
              // pair straddles batch boundary: scalar stores to both combos
              *(f16*)(vbase + (hhw * 2 + 0) * 3072 + d * 48 + 16 * 2) =
                  (f16)acc[mt][nt][r];
              *(f16*)(vbase + (hhw * 2 + 1) * 3072 + d * 48 + 0) = (f16)acc[mt][nt][r + 1];
            } else if (mrow < 34) {
              int bbw = mrow >= 17 ? 1 : 0;
              int m = mrow - 17 * bbw;
              *(u32*)(vbase + (hhw * 2 + bbw) * 3072 + d * 48 + m * 2) =
                  bcu(pkrtz(acc[mt][nt][r], acc[mt][nt][r + 1]));
            }
          }
        }
      }
    } else {
      unsigned char* kbase = lds + KS_OFF + buf * 9792;
#pragma unroll
      for (int mt = 0; mt < 3; ++mt) {
#pragma unroll
        for (int nt = 0; nt < 4; ++nt) {
          int d = nt * 16 + l15;
#pragma unroll
          for (int r = 0; r < 4; ++r) {
            int mrow = mt * 16 + lhi * 4 + r;
            if (mrow < 34) {
              int bbw = mrow >= 17 ? 1 : 0;
              int m = mrow - 17 * bbw;
              *(f16*)(kbase + (hhw * 2 + bbw) * 2448 + m * 144 + d * 2) =
                  (f16)acc[mt][nt][r];
            }
          }
        }
      }
    }
    __syncthreads();

    // ---- attention: combo = wv ----
    const unsigned char* ksb = lds + KS_OFF + buf * 9792 + wv * 2448;
    const unsigned char* vtb = lds + VT_OFF + buf * 12288 + wv * 3072;
    f16x8 kf0[2], kf1[2], vf[4];
#pragma unroll
    for (int c = 0; c < 2; ++c) {
      kf0[c] = *(const f16x8*)(ksb + l15 * 144 + c * 64 + lhi * 16);
      kf1[c] = *(const f16x8*)(ksb + 16 * 144 + c * 64 + lhi * 16);
    }
#pragma unroll
    for (int dt = 0; dt < 4; ++dt)
      vf[dt] = *(const f16x8*)(vtb + (dt * 16 + l15) * 48 + lhi * 16);

    float* ob = out + (size_t)b * 77 * 512 + head_a * 64;
#pragma unroll
    for (int nt = 0; nt < 5; ++nt) {
      f32x4 z = {0.f, 0.f, 0.f, 0.f};
      f32x4 s0 = z, s1 = z;
      s0 = __builtin_amdgcn_mfma_f32_16x16x32_f16(kf0[0], qf[nt][0], s0, 0, 0, 0);
      s0 = __builtin_amdgcn_mfma_f32_16x16x32_f16(kf0[1], qf[nt][1], s0, 0, 0, 0);
      s1 = __builtin_amdgcn_mfma_f32_16x16x32_f16(kf1[0], qf[nt][0], s1, 0, 0, 0);
      s1 = __builtin_amdgcn_mfma_f32_16x16x32_f16(kf1[1], qf[nt][1], s1, 0, 0, 0);
      float mx = fmaxf(fmaxf(s0[0], s0[1]), fmaxf(s0[2], s0[3]));
      mx = fmaxf(mx, __shfl_xor(mx, 16));
      mx = fmaxf(mx, __shfl_xor(mx, 32));
      mx = fmaxf(mx, s1[0]);
      float e0[4];
#pragma unroll
      for (int r = 0; r < 4; ++r) e0[r] = exp2f((s0[r] - mx) * C2);
      float e1 = exp2f((s1[0] - mx) * C2);
      float sm = e0[0] + e0[1] + e0[2] + e0[3];
      sm += __shfl_xor(sm, 16);
      sm += __shfl_xor(sm, 32);
      sm += e1;
      float inv = fastrcp(sm);
#pragma unroll
      for (int r = 0; r < 4; ++r) e0[r] *= inv;
      e1 *= inv;
      f16x8 pfrag = repack_frag(e0[0], e0[1], e0[2], e0[3], (lhi == 0) ? e1 : 0.f, l15, lhi);
#pragma unroll
      for (int dt = 0; dt < 4; ++dt) {
        f32x4 o = {0.f, 0.f, 0.f, 0.f};
        o = __builtin_amdgcn_mfma_f32_16x16x32_f16(pfrag, vf[dt], o, 0, 0, 0);
#pragma unroll
        for (int r = 0; r < 4; ++r) {
          int n = nt * 16 + lhi * 4 + r;
          if (n < 77) ob[(size_t)n * 512 + dt * 16 + l15] = o[r];
        }
      }
    }
  }
}

extern "C" void kernel_launch(void* const* d_in, const int* in_sizes, int n_in,
                              void* d_out, int out_size, void* d_ws, size_t ws_size,
                              hipStream_t stream) {
  const float* xf = (const float*)d_in[0];
  const float* x = (const float*)d_in[1];
  const float* tn_g = (const float*)d_in[2];
  const float* tn_b = (const float*)d_in[3];
  const float* n_g = (const float*)d_in[4];
  const float* n_b = (const float*)d_in[5];
  const float* Wq = (const float*)d_in[6];
  const float* bq = (const float*)d_in[7];
  const float* Wk = (const float*)d_in[8];
  const float* bk = (const float*)d_in[9];
  const float* Wv = (const float*)d_in[10];
  const float* bv = (const float*)d_in[11];
  float* out = (float*)d_out;

  char* ws = (char*)d_ws;
  f16* q16h = (f16*)ws;                      // 8*16*77*64*2 = 1,261,568 B (+1024 pad)
  f16* Wcat = (f16*)(ws + 1262592);          // 1024*512*2   = 1,048,576 B
  float* bcat = (float*)(ws + 2311168);      // 1024*4       = 4,096 B

  prep_q_k<<<416, 256, 0, stream>>>(xf, tn_g, tn_b, Wq, bq, Wk, bk, Wv, bv,
                                    Wcat, bcat, q16h);
  fused_k<<<1944, 256, 0, stream>>>(x, n_g, n_b, Wcat, bcat, q16h, out);
}

// Round 17
// 373.806 us; speedup vs baseline: 2.1768x; 1.0160x over previous
//
#include <hip/hip_runtime.h>
#include <stdint.h>

#define D 512

typedef _Float16 f16;
typedef f16 f16x8 __attribute__((ext_vector_type(8)));
typedef f16 h2 __attribute__((ext_vector_type(2)));
typedef float f32x4 __attribute__((ext_vector_type(4)));
typedef unsigned int u32;
typedef u32 u32x4 __attribute__((ext_vector_type(4)));

static __device__ __forceinline__ u32 bcu(h2 h) { return __builtin_bit_cast(u32, h); }
static __device__ __forceinline__ h2 pkrtz(float a, float b) {
  return __builtin_bit_cast(h2, __builtin_amdgcn_cvt_pkrtz(a, b));
}
static __device__ __forceinline__ f16x8 frag4(u32 w0, u32 w1, u32 w2, u32 w3) {
  u32x4 u = {w0, w1, w2, w3};
  return __builtin_bit_cast(f16x8, u);
}
static __device__ __forceinline__ float fastrcp(float x) {
#if __has_builtin(__builtin_amdgcn_rcpf)
  return __builtin_amdgcn_rcpf(x);
#else
  return 1.0f / x;
#endif
}

// lhi-repack (verified R5-R16): C-layout tile pair -> A-frag (k=m, m 17..31 = 0).
static __device__ __forceinline__ f16x8 repack_frag(float c0, float c1, float c2, float c3,
                                                    float v16, int l15, int lhi) {
  u32 t0a = bcu(pkrtz(c0, c1)), t0b = bcu(pkrtz(c2, c3));
  u32 t1a = bcu(pkrtz(v16, 0.f));
  int srcA = (((lhi * 2) & 3) << 4) | l15;
  int srcB = (((lhi * 2 + 1) & 3) << 4) | l15;
  u32 a0 = (u32)__shfl((int)t0a, srcA);
  u32 a1 = (u32)__shfl((int)t0b, srcA);
  u32 a2 = (u32)__shfl((int)t1a, srcA);
  u32 b0 = (u32)__shfl((int)t0a, srcB);
  u32 b1 = (u32)__shfl((int)t0b, srcB);
  u32 b2 = (u32)__shfl((int)t1a, srcB);
  bool lo = lhi < 2;
  return frag4(lo ? a0 : a2, lo ? a1 : 0u, lo ? b0 : b2, lo ? b1 : 0u);
}

// ---------------- prep_q: blocks 0..255 = Wcat/bcat prep; 256..415 = qproj ----------------
__global__ __launch_bounds__(256) void prep_q_k(
    const float* __restrict__ xf, const float* __restrict__ tn_g,
    const float* __restrict__ tn_b, const float* __restrict__ Wq,
    const float* __restrict__ bq, const float* __restrict__ Wk,
    const float* __restrict__ bk, const float* __restrict__ Wv,
    const float* __restrict__ bv, f16* __restrict__ Wcat,
    float* __restrict__ bcat, f16* __restrict__ q16h) {
  __shared__ __align__(16) unsigned char lds[16384];
  const int bid = blockIdx.x, tid = threadIdx.x;
  const int wv = tid >> 6, lane = tid & 63;
  if (bid < 256) {
    int row = bid * 4 + wv;
    int h = row >> 7, kvs = (row >> 6) & 1, d = row & 63;
    int srow = h * 64 + d;
    const float* src = (kvs ? Wv : Wk) + (size_t)srow * D;
    f32x4 a = *(const f32x4*)(src + lane * 8);
    f32x4 c = *(const f32x4*)(src + lane * 8 + 4);
    uint4 u;
    u.x = bcu(pkrtz(a[0], a[1]));
    u.y = bcu(pkrtz(a[2], a[3]));
    u.z = bcu(pkrtz(c[0], c[1]));
    u.w = bcu(pkrtz(c[2], c[3]));
    *reinterpret_cast<uint4*>(Wcat + (size_t)row * D + lane * 8) = u;
    if (lane == 0) bcat[row] = (kvs ? bv : bk)[srow];
    return;
  }
  const int bid2 = bid - 256;          // 0..159
  const int bs = bid2 & 15;
  const int g = bid2 >> 4;             // 0..9
  const int n0 = (g >> 1) * 16;
  const int ch = g & 1;
  const int l15 = lane & 15, lhi = lane >> 4;

  for (int rr = wv; rr < 16; rr += 4) {
    int srcn = n0 + rr;
    if (srcn > 76) srcn = 76;
    const f32x4* xr = (const f32x4*)(xf + ((size_t)(bs * 77 + srcn)) * D);
    f32x4 va = xr[lane * 2], vb = xr[lane * 2 + 1];
    float s = va[0] + va[1] + va[2] + va[3] + vb[0] + vb[1] + vb[2] + vb[3];
    float sq = va[0] * va[0] + va[1] * va[1] + va[2] * va[2] + va[3] * va[3] +
               vb[0] * vb[0] + vb[1] * vb[1] + vb[2] * vb[2] + vb[3] * vb[3];
#pragma unroll
    for (int off = 32; off; off >>= 1) {
      s += __shfl_xor(s, off);
      sq += __shfl_xor(sq, off);
    }
    float mu = s * (1.0f / 512.0f);
    float var = sq * (1.0f / 512.0f) - mu * mu;
    float rstd = rsqrtf(var + 1e-5f);
    f32x4 ga = ((const f32x4*)tn_g)[lane * 2], gb = ((const f32x4*)tn_g)[lane * 2 + 1];
    f32x4 ba = ((const f32x4*)tn_b)[lane * 2], bb = ((const f32x4*)tn_b)[lane * 2 + 1];
    uint4 u;
    u.x = bcu(pkrtz((va[0] - mu) * rstd * ga[0] + ba[0], (va[1] - mu) * rstd * ga[1] + ba[1]));
    u.y = bcu(pkrtz((va[2] - mu) * rstd * ga[2] + ba[2], (va[3] - mu) * rstd * ga[3] + ba[3]));
    u.z = bcu(pkrtz((vb[0] - mu) * rstd * gb[0] + bb[0], (vb[1] - mu) * rstd * gb[1] + bb[1]));
    u.w = bcu(pkrtz((vb[2] - mu) * rstd * gb[2] + bb[2], (vb[3] - mu) * rstd * gb[3] + bb[3]));
    *reinterpret_cast<uint4*>(lds + rr * 1024 + ((lane * 16) ^ ((rr & 7) << 4))) = u;
  }
  __syncthreads();

  f32x4 acc[4];
#pragma unroll
  for (int nt = 0; nt < 4; ++nt) {
    float bias = bq[ch * 256 + wv * 64 + nt * 16 + l15];
    acc[nt] = (f32x4){bias, bias, bias, bias};
  }
#pragma unroll 4
  for (int ks = 0; ks < 16; ++ks) {
    f16x8 af = *(const f16x8*)(lds + l15 * 1024 + ((ks * 64 + lhi * 16) ^ ((l15 & 7) << 4)));
#pragma unroll
    for (int nt = 0; nt < 4; ++nt) {
      const float* wr = Wq + (size_t)(ch * 256 + wv * 64 + nt * 16 + l15) * D + ks * 32 + lhi * 8;
      f32x4 wa = *(const f32x4*)wr, wb = *(const f32x4*)(wr + 4);
      f16x8 bf = frag4(bcu(pkrtz(wa[0], wa[1])), bcu(pkrtz(wa[2], wa[3])),
                       bcu(pkrtz(wb[0], wb[1])), bcu(pkrtz(wb[2], wb[3])));
      acc[nt] = __builtin_amdgcn_mfma_f32_16x16x32_f16(af, bf, acc[nt], 0, 0, 0);
    }
  }
#pragma unroll
  for (int nt = 0; nt < 4; ++nt) {
    int col = ch * 256 + wv * 64 + nt * 16 + l15;
    int h = col >> 6, d = col & 63;
    f16* base = q16h + ((size_t)(h * 16 + bs) * 77) * 64;
#pragma unroll
    for (int r = 0; r < 4; ++r) {
      int n = n0 + lhi * 4 + r;
      if (n < 77) base[n * 64 + d] = (f16)acc[nt][r];
    }
  }
}

// ---------------- fused (R17 = R16 math, phases reordered: proj(hp+1) BEFORE attn(hp)) --
// LDS identical to R10/R16. Per loop iter: proj(hp+1)->buf^1 issued first (its weight-load
// latency + store drain hide under attn), then attn(hp) from buf (already complete since
// LAST barrier -> no wait at entry), then ONE barrier. NO frag hoisting across proj
// (R9's spill trap): attn loads qf/kf/vf after proj; register lifetimes disjoint.
#define XN_OFF 0
#define KS_OFF 34816
#define VT_OFF 54400
#define LDS_TOTAL 79040

static __device__ __forceinline__ void do_proj(
    const f16* __restrict__ Wcat, const float* __restrict__ bcat,
    unsigned char* lds, int hp, int buf, int wv, int l15, int lhi, int hhw, int isv) {
  f32x4 acc[3][4];
#pragma unroll
  for (int nt = 0; nt < 4; ++nt) {
    float bias = bcat[hp * 256 + wv * 64 + nt * 16 + l15];
    f32x4 bi = {bias, bias, bias, bias};
#pragma unroll
    for (int mt = 0; mt < 3; ++mt) acc[mt][nt] = bi;
  }
  const f16* wbase = Wcat + (size_t)(hp * 256 + wv * 64 + l15) * D;
  // 3-slot rotating prefetch (R10-verified)
  f16x8 bf[3][4];
#pragma unroll
  for (int p = 0; p < 3; ++p)
#pragma unroll
    for (int nt = 0; nt < 4; ++nt)
      bf[p][nt] = *(const f16x8*)(wbase + (size_t)nt * 16 * D + p * 32 + lhi * 8);
#pragma unroll
  for (int ks = 0; ks < 16; ++ks) {
    const int cur = ks % 3;
#pragma unroll
    for (int mt = 0; mt < 3; ++mt) {
      int arow = mt * 16 + l15;
      f16x8 af = *(const f16x8*)(lds + XN_OFF + arow * 1024 +
                                 ((ks * 64 + lhi * 16) ^ ((arow & 7) << 4)));
#pragma unroll
      for (int nt = 0; nt < 4; ++nt)
        acc[mt][nt] =
            __builtin_amdgcn_mfma_f32_16x16x32_f16(af, bf[cur][nt], acc[mt][nt], 0, 0, 0);
    }
    if (ks < 13) {
#pragma unroll
      for (int nt = 0; nt < 4; ++nt)
        bf[cur][nt] = *(const f16x8*)(wbase + (size_t)nt * 16 * D + (ks + 3) * 32 + lhi * 8);
    }
  }
  // store K/V tiles into LDS buffer `buf` (R10-verified layout)
  if (isv) {
    unsigned char* vbase = lds + VT_OFF + buf * 12288;
#pragma unroll
    for (int mt = 0; mt < 3; ++mt) {
#pragma unroll
      for (int nt = 0; nt < 4; ++nt) {
        int d = nt * 16 + l15;
#pragma unroll
        for (int r = 0; r < 4; r += 2) {
          int mrow = mt * 16 + lhi * 4 + r;  // even
          if (mrow == 16) {
            *(f16*)(vbase + (hhw * 2 + 0) * 3072 + d * 48 + 16 * 2) = (f16)acc[mt][nt][r];
            *(f16*)(vbase + (hhw * 2 + 1) * 3072 + d * 48 + 0) = (f16)acc[mt][nt][r + 1];
          } else if (mrow < 34) {
            int bbw = mrow >= 17 ? 1 : 0;
            int m = mrow - 17 * bbw;
            *(u32*)(vbase + (hhw * 2 + bbw) * 3072 + d * 48 + m * 2) =
                bcu(pkrtz(acc[mt][nt][r], acc[mt][nt][r + 1]));
          }
        }
      }
    }
  } else {
    unsigned char* kbase = lds + KS_OFF + buf * 9792;
#pragma unroll
    for (int mt = 0; mt < 3; ++mt) {
#pragma unroll
      for (int nt = 0; nt < 4; ++nt) {
        int d = nt * 16 + l15;
#pragma unroll
        for (int r = 0; r < 4; ++r) {
          int mrow = mt * 16 + lhi * 4 + r;
          if (mrow < 34) {
            int bbw = mrow >= 17 ? 1 : 0;
            int m = mrow - 17 * bbw;
            *(f16*)(kbase + (hhw * 2 + bbw) * 2448 + m * 144 + d * 2) = (f16)acc[mt][nt][r];
          }
        }
      }
    }
  }
}

__global__ __launch_bounds__(256, 2) void fused_k(
    const float* __restrict__ x, const float* __restrict__ n_g,
    const float* __restrict__ n_b, const f16* __restrict__ Wcat,
    const float* __restrict__ bcat, const f16* __restrict__ q16h,
    float* __restrict__ out) {
  __shared__ __align__(16) unsigned char lds[LDS_TOTAL];
  const int b0 = blockIdx.x * 2;
  const int tid = threadIdx.x, wv = tid >> 6, lane = tid & 63;
  const int l15 = lane & 15, lhi = lane >> 4;

  // zero VT (both buffers + slack): PV k in [17,24) must read 0
  {
    uint4 z;
    z.x = z.y = z.z = z.w = 0u;
    for (int i = tid; i < 1540; i += 256)
      *reinterpret_cast<uint4*>(lds + VT_OFF + i * 16) = z;
  }

  // Phase 1: LayerNorm -> xn f16 rows 0..33 (swizzled)
  for (int rr = wv; rr < 34; rr += 4) {
    const f32x4* xr = (const f32x4*)(x + ((size_t)(b0 * 17 + rr)) * D);
    f32x4 va = xr[lane * 2], vb = xr[lane * 2 + 1];
    float s = va[0] + va[1] + va[2] + va[3] + vb[0] + vb[1] + vb[2] + vb[3];
    float sq = va[0] * va[0] + va[1] * va[1] + va[2] * va[2] + va[3] * va[3] +
               vb[0] * vb[0] + vb[1] * vb[1] + vb[2] * vb[2] + vb[3] * vb[3];
#pragma unroll
    for (int off = 32; off; off >>= 1) {
      s += __shfl_xor(s, off);
      sq += __shfl_xor(sq, off);
    }
    float mu = s * (1.0f / 512.0f);
    float var = sq * (1.0f / 512.0f) - mu * mu;
    float rstd = rsqrtf(var + 1e-5f);
    f32x4 ga = ((const f32x4*)n_g)[lane * 2], gb = ((const f32x4*)n_g)[lane * 2 + 1];
    f32x4 ba = ((const f32x4*)n_b)[lane * 2], bb = ((const f32x4*)n_b)[lane * 2 + 1];
    uint4 u;
    u.x = bcu(pkrtz((va[0] - mu) * rstd * ga[0] + ba[0], (va[1] - mu) * rstd * ga[1] + ba[1]));
    u.y = bcu(pkrtz((va[2] - mu) * rstd * ga[2] + ba[2], (va[3] - mu) * rstd * ga[3] + ba[3]));
    u.z = bcu(pkrtz((vb[0] - mu) * rstd * gb[0] + bb[0], (vb[1] - mu) * rstd * gb[1] + bb[1]));
    u.w = bcu(pkrtz((vb[2] - mu) * rstd * gb[2] + bb[2], (vb[3] - mu) * rstd * gb[3] + bb[3]));
    *reinterpret_cast<uint4*>(lds + XN_OFF + rr * 1024 + ((lane * 16) ^ ((rr & 7) << 4))) = u;
  }
  __syncthreads();

  const int hhw = wv >> 1, isv = wv & 1;  // projection role (cols)
  const int bb = wv & 1;                  // attention combo = wv
  const int b = b0 + bb, bs = b & 15;
  const float C2 = 0.18033688011112042f;  // log2(e)/8

  // prologue: project head-pair 0 into buffer 0
  do_proj(Wcat, bcat, lds, 0, 0, wv, l15, lhi, hhw, isv);
  __syncthreads();

  for (int hp = 0; hp < 4; ++hp) {
    const int buf = hp & 1;
    const int head_a = hp * 2 + hhw;

    // ---- project NEXT head-pair first: latency + store drain hide under attn ----
    if (hp < 3)
      do_proj(Wcat, bcat, lds, hp + 1, buf ^ 1, wv, l15, lhi, hhw, isv);

    // ---- attention: combo = wv (buf contents complete since last barrier) ----
    const f16* qb = q16h + ((size_t)(head_a * 16 + bs) * 77) * 64;
    f16x8 qf[5][2];
#pragma unroll
    for (int nt = 0; nt < 5; ++nt) {
      int nq = nt * 16 + l15;
      if (nq > 76) nq = 76;
      qf[nt][0] = *(const f16x8*)(qb + nq * 64 + lhi * 8);
      qf[nt][1] = *(const f16x8*)(qb + nq * 64 + 32 + lhi * 8);
    }
    const unsigned char* ksb = lds + KS_OFF + buf * 9792 + wv * 2448;
    const unsigned char* vtb = lds + VT_OFF + buf * 12288 + wv * 3072;
    f16x8 kf0[2], kf1[2], vf[4];
#pragma unroll
    for (int c = 0; c < 2; ++c) {
      kf0[c] = *(const f16x8*)(ksb + l15 * 144 + c * 64 + lhi * 16);
      kf1[c] = *(const f16x8*)(ksb + 16 * 144 + c * 64 + lhi * 16);
    }
#pragma unroll
    for (int dt = 0; dt < 4; ++dt)
      vf[dt] = *(const f16x8*)(vtb + (dt * 16 + l15) * 48 + lhi * 16);

    float* ob = out + (size_t)b * 77 * 512 + head_a * 64;
#pragma unroll
    for (int nt = 0; nt < 5; ++nt) {
      f32x4 z = {0.f, 0.f, 0.f, 0.f};
      f32x4 s0 = z, s1 = z;
      s0 = __builtin_amdgcn_mfma_f32_16x16x32_f16(kf0[0], qf[nt][0], s0, 0, 0, 0);
      s0 = __builtin_amdgcn_mfma_f32_16x16x32_f16(kf0[1], qf[nt][1], s0, 0, 0, 0);
      s1 = __builtin_amdgcn_mfma_f32_16x16x32_f16(kf1[0], qf[nt][0], s1, 0, 0, 0);
      s1 = __builtin_amdgcn_mfma_f32_16x16x32_f16(kf1[1], qf[nt][1], s1, 0, 0, 0);
      float mx = fmaxf(fmaxf(s0[0], s0[1]), fmaxf(s0[2], s0[3]));
      mx = fmaxf(mx, __shfl_xor(mx, 16));
      mx = fmaxf(mx, __shfl_xor(mx, 32));
      mx = fmaxf(mx, s1[0]);
      float e0[4];
#pragma unroll
      for (int r = 0; r < 4; ++r) e0[r] = exp2f((s0[r] - mx) * C2);
      float e1 = exp2f((s1[0] - mx) * C2);
      float sm = e0[0] + e0[1] + e0[2] + e0[3];
      sm += __shfl_xor(sm, 16);
      sm += __shfl_xor(sm, 32);
      sm += e1;
      float inv = fastrcp(sm);
#pragma unroll
      for (int r = 0; r < 4; ++r) e0[r] *= inv;
      e1 *= inv;
      f16x8 pfrag = repack_frag(e0[0], e0[1], e0[2], e0[3], (lhi == 0) ? e1 : 0.f, l15, lhi);
#pragma unroll
      for (int dt = 0; dt < 4; ++dt) {
        f32x4 o = {0.f, 0.f, 0.f, 0.f};
        o = __builtin_amdgcn_mfma_f32_16x16x32_f16(pfrag, vf[dt], o, 0, 0, 0);
#pragma unroll
        for (int r = 0; r < 4; ++r) {
          int n = nt * 16 + lhi * 4 + r;
          if (n < 77) ob[(size_t)n * 512 + dt * 16 + l15] = o[r];
        }
      }
    }

    if (hp < 3) __syncthreads();
  }
}

extern "C" void kernel_launch(void* const* d_in, const int* in_sizes, int n_in,
                              void* d_out, int out_size, void* d_ws, size_t ws_size,
                              hipStream_t stream) {
  const float* xf = (const float*)d_in[0];
  const float* x = (const float*)d_in[1];
  const float* tn_g = (const float*)d_in[2];
  const float* tn_b = (const float*)d_in[3];
  const float* n_g = (const float*)d_in[4];
  const float* n_b = (const float*)d_in[5];
  const float* Wq = (const float*)d_in[6];
  const float* bq = (const float*)d_in[7];
  const float* Wk = (const float*)d_in[8];
  const float* bk = (const float*)d_in[9];
  const float* Wv = (const float*)d_in[10];
  const float* bv = (const float*)d_in[11];
  float* out = (float*)d_out;

  char* ws = (char*)d_ws;
  f16* q16h = (f16*)ws;                      // 8*16*77*64*2 = 1,261,568 B (+1024 pad)
  f16* Wcat = (f16*)(ws + 1262592);          // 1024*512*2   = 1,048,576 B
  float* bcat = (float*)(ws + 2311168);      // 1024*4       = 4,096 B

  prep_q_k<<<416, 256, 0, stream>>>(xf, tn_g, tn_b, Wq, bq, Wk, bk, Wv, bv,
                                    Wcat, bcat, q16h);
  fused_k<<<1944, 256, 0, stream>>>(x, n_g, n_b, Wcat, bcat, q16h, out);
}

// Round 18
// 290.721 us; speedup vs baseline: 2.7989x; 1.2858x over previous
//
#include <hip/hip_runtime.h>
#include <stdint.h>

#define D 512

typedef _Float16 f16;
typedef f16 f16x8 __attribute__((ext_vector_type(8)));
typedef f16 h2 __attribute__((ext_vector_type(2)));
typedef float f32x4 __attribute__((ext_vector_type(4)));
typedef unsigned int u32;
typedef u32 u32x4 __attribute__((ext_vector_type(4)));

static __device__ __forceinline__ u32 bcu(h2 h) { return __builtin_bit_cast(u32, h); }
static __device__ __forceinline__ h2 pkrtz(float a, float b) {
  return __builtin_bit_cast(h2, __builtin_amdgcn_cvt_pkrtz(a, b));
}
static __device__ __forceinline__ f16x8 frag4(u32 w0, u32 w1, u32 w2, u32 w3) {
  u32x4 u = {w0, w1, w2, w3};
  return __builtin_bit_cast(f16x8, u);
}
static __device__ __forceinline__ float fastrcp(float x) {
#if __has_builtin(__builtin_amdgcn_rcpf)
  return __builtin_amdgcn_rcpf(x);
#else
  return 1.0f / x;
#endif
}

// lhi-repack (verified R5-R17): C-layout tile pair -> A-frag (k=m, m 17..31 = 0).
static __device__ __forceinline__ f16x8 repack_frag(float c0, float c1, float c2, float c3,
                                                    float v16, int l15, int lhi) {
  u32 t0a = bcu(pkrtz(c0, c1)), t0b = bcu(pkrtz(c2, c3));
  u32 t1a = bcu(pkrtz(v16, 0.f));
  int srcA = (((lhi * 2) & 3) << 4) | l15;
  int srcB = (((lhi * 2 + 1) & 3) << 4) | l15;
  u32 a0 = (u32)__shfl((int)t0a, srcA);
  u32 a1 = (u32)__shfl((int)t0b, srcA);
  u32 a2 = (u32)__shfl((int)t1a, srcA);
  u32 b0 = (u32)__shfl((int)t0a, srcB);
  u32 b1 = (u32)__shfl((int)t0b, srcB);
  u32 b2 = (u32)__shfl((int)t1a, srcB);
  bool lo = lhi < 2;
  return frag4(lo ? a0 : a2, lo ? a1 : 0u, lo ? b0 : b2, lo ? b1 : 0u);
}

// ---------------- prep_q: blocks 0..255 = Wcat2 swizzle; 256..415 = qproj ----------------
// Wcat2 layout: [slab 0..15][ks 0..15][nt 0..3][chunk 0..63] of 16B chunks,
// chunk = l15*4 + lhi; data = W[col = slab*64 + nt*16 + l15][k = ks*32 + lhi*8 .. +8] f16.
// Every fused bf load = one contiguous 1KB segment (fully coalesced).
__global__ __launch_bounds__(256) void prep_q_k(
    const float* __restrict__ xf, const float* __restrict__ tn_g,
    const float* __restrict__ tn_b, const float* __restrict__ Wq,
    const float* __restrict__ bq, const float* __restrict__ Wk,
    const float* __restrict__ bk, const float* __restrict__ Wv,
    const float* __restrict__ bv, f16* __restrict__ Wcat2,
    float* __restrict__ bcat, f16* __restrict__ q16h) {
  __shared__ __align__(16) unsigned char lds[16384];
  const int bid = blockIdx.x, tid = threadIdx.x;
  const int wv = tid >> 6, lane = tid & 63;
  if (bid < 256) {
    const int s = bid >> 4, ks = bid & 15;
    const int nt = tid >> 6;               // 4 nt x 64 chunk-threads
    const int cl = tid & 63;               // chunk = cl; cl = l15*4 + lhi
    const int l15 = cl >> 2, lhi = cl & 3;
    int c = s * 64 + nt * 16 + l15;
    int h = c >> 7, kv = (c >> 6) & 1, d = c & 63;
    const float* src = (kv ? Wv : Wk) + (size_t)(h * 64 + d) * D + ks * 32 + lhi * 8;
    f32x4 a = *(const f32x4*)src;
    f32x4 cc = *(const f32x4*)(src + 4);
    uint2 u;
    u.x = bcu(pkrtz(a[0], a[1]));
    u.y = bcu(pkrtz(a[2], a[3]));
    uint2 v;
    v.x = bcu(pkrtz(cc[0], cc[1]));
    v.y = bcu(pkrtz(cc[2], cc[3]));
    uint4 out16;
    out16.x = u.x; out16.y = u.y; out16.z = v.x; out16.w = v.y;
    *reinterpret_cast<uint4*>(Wcat2 + ((size_t)((s * 16 + ks) * 4 + nt) * 64 + cl) * 8) = out16;
    if (ks == 0 && lhi == 0) {
      // bcat for this slab's cols (one thread per (nt,l15))
      bcat[c] = (kv ? bv : bk)[h * 64 + d];
    }
    return;
  }
  // ---- qproj: q16h[h][bs][n][64] = LN(xf) @ Wq^T + bq ----
  const int bid2 = bid - 256;          // 0..159
  const int bs = bid2 & 15;
  const int g = bid2 >> 4;             // 0..9
  const int n0 = (g >> 1) * 16;
  const int ch = g & 1;
  const int l15 = lane & 15, lhi = lane >> 4;

  for (int rr = wv; rr < 16; rr += 4) {
    int srcn = n0 + rr;
    if (srcn > 76) srcn = 76;
    const f32x4* xr = (const f32x4*)(xf + ((size_t)(bs * 77 + srcn)) * D);
    f32x4 va = xr[lane * 2], vb = xr[lane * 2 + 1];
    float s = va[0] + va[1] + va[2] + va[3] + vb[0] + vb[1] + vb[2] + vb[3];
    float sq = va[0] * va[0] + va[1] * va[1] + va[2] * va[2] + va[3] * va[3] +
               vb[0] * vb[0] + vb[1] * vb[1] + vb[2] * vb[2] + vb[3] * vb[3];
#pragma unroll
    for (int off = 32; off; off >>= 1) {
      s += __shfl_xor(s, off);
      sq += __shfl_xor(sq, off);
    }
    float mu = s * (1.0f / 512.0f);
    float var = sq * (1.0f / 512.0f) - mu * mu;
    float rstd = rsqrtf(var + 1e-5f);
    f32x4 ga = ((const f32x4*)tn_g)[lane * 2], gb = ((const f32x4*)tn_g)[lane * 2 + 1];
    f32x4 ba = ((const f32x4*)tn_b)[lane * 2], bb = ((const f32x4*)tn_b)[lane * 2 + 1];
    uint4 u;
    u.x = bcu(pkrtz((va[0] - mu) * rstd * ga[0] + ba[0], (va[1] - mu) * rstd * ga[1] + ba[1]));
    u.y = bcu(pkrtz((va[2] - mu) * rstd * ga[2] + ba[2], (va[3] - mu) * rstd * ga[3] + ba[3]));
    u.z = bcu(pkrtz((vb[0] - mu) * rstd * gb[0] + bb[0], (vb[1] - mu) * rstd * gb[1] + bb[1]));
    u.w = bcu(pkrtz((vb[2] - mu) * rstd * gb[2] + bb[2], (vb[3] - mu) * rstd * gb[3] + bb[3]));
    *reinterpret_cast<uint4*>(lds + rr * 1024 + ((lane * 16) ^ ((rr & 7) << 4))) = u;
  }
  __syncthreads();

  f32x4 acc[4];
#pragma unroll
  for (int nt = 0; nt < 4; ++nt) {
    float bias = bq[ch * 256 + wv * 64 + nt * 16 + l15];
    acc[nt] = (f32x4){bias, bias, bias, bias};
  }
#pragma unroll 4
  for (int ks = 0; ks < 16; ++ks) {
    f16x8 af = *(const f16x8*)(lds + l15 * 1024 + ((ks * 64 + lhi * 16) ^ ((l15 & 7) << 4)));
#pragma unroll
    for (int nt = 0; nt < 4; ++nt) {
      const float* wr = Wq + (size_t)(ch * 256 + wv * 64 + nt * 16 + l15) * D + ks * 32 + lhi * 8;
      f32x4 wa = *(const f32x4*)wr, wb = *(const f32x4*)(wr + 4);
      f16x8 bf = frag4(bcu(pkrtz(wa[0], wa[1])), bcu(pkrtz(wa[2], wa[3])),
                       bcu(pkrtz(wb[0], wb[1])), bcu(pkrtz(wb[2], wb[3])));
      acc[nt] = __builtin_amdgcn_mfma_f32_16x16x32_f16(af, bf, acc[nt], 0, 0, 0);
    }
  }
#pragma unroll
  for (int nt = 0; nt < 4; ++nt) {
    int col = ch * 256 + wv * 64 + nt * 16 + l15;
    int h = col >> 6, d = col & 63;
    f16* base = q16h + ((size_t)(h * 16 + bs) * 77) * 64;
#pragma unroll
    for (int r = 0; r < 4; ++r) {
      int n = n0 + lhi * 4 + r;
      if (n < 77) base[n * 64 + d] = (f16)acc[nt][r];
    }
  }
}

// ---------------- fused (R18 = R17 + coalesced pre-swizzled weight loads) ----------------
#define XN_OFF 0
#define KS_OFF 34816
#define VT_OFF 54400
#define LDS_TOTAL 79040

static __device__ __forceinline__ void do_proj(
    const f16* __restrict__ Wcat2, const float* __restrict__ bcat,
    unsigned char* lds, int hp, int buf, int wv, int l15, int lhi, int hhw, int isv,
    int chunk) {
  f32x4 acc[3][4];
#pragma unroll
  for (int nt = 0; nt < 4; ++nt) {
    float bias = bcat[hp * 256 + wv * 64 + nt * 16 + l15];
    f32x4 bi = {bias, bias, bias, bias};
#pragma unroll
    for (int mt = 0; mt < 3; ++mt) acc[mt][nt] = bi;
  }
  // pre-swizzled weights: slab = hp*4 + wv; frag addr = ((slab*16+ks)*4+nt)*1024 + chunk*16
  const f16* wbase = Wcat2 + (size_t)(hp * 4 + wv) * 32768;  // 16 ks * 4 nt * 512 f16
  // 3-slot rotating prefetch
  f16x8 bf[3][4];
#pragma unroll
  for (int p = 0; p < 3; ++p)
#pragma unroll
    for (int nt = 0; nt < 4; ++nt)
      bf[p][nt] = *(const f16x8*)(wbase + ((p * 4 + nt) * 64 + chunk) * 8);
#pragma unroll
  for (int ks = 0; ks < 16; ++ks) {
    const int cur = ks % 3;
#pragma unroll
    for (int mt = 0; mt < 3; ++mt) {
      int arow = mt * 16 + l15;
      f16x8 af = *(const f16x8*)(lds + XN_OFF + arow * 1024 +
                                 ((ks * 64 + lhi * 16) ^ ((arow & 7) << 4)));
#pragma unroll
      for (int nt = 0; nt < 4; ++nt)
        acc[mt][nt] =
            __builtin_amdgcn_mfma_f32_16x16x32_f16(af, bf[cur][nt], acc[mt][nt], 0, 0, 0);
    }
    if (ks < 13) {
#pragma unroll
      for (int nt = 0; nt < 4; ++nt)
        bf[cur][nt] = *(const f16x8*)(wbase + (((ks + 3) * 4 + nt) * 64 + chunk) * 8);
    }
  }
  if (isv) {
    unsigned char* vbase = lds + VT_OFF + buf * 12288;
#pragma unroll
    for (int mt = 0; mt < 3; ++mt) {
#pragma unroll
      for (int nt = 0; nt < 4; ++nt) {
        int d = nt * 16 + l15;
#pragma unroll
        for (int r = 0; r < 4; r += 2) {
          int mrow = mt * 16 + lhi * 4 + r;  // even
          if (mrow == 16) {
            *(f16*)(vbase + (hhw * 2 + 0) * 3072 + d * 48 + 16 * 2) = (f16)acc[mt][nt][r];
            *(f16*)(vbase + (hhw * 2 + 1) * 3072 + d * 48 + 0) = (f16)acc[mt][nt][r + 1];
          } else if (mrow < 34) {
            int bbw = mrow >= 17 ? 1 : 0;
            int m = mrow - 17 * bbw;
            *(u32*)(vbase + (hhw * 2 + bbw) * 3072 + d * 48 + m * 2) =
                bcu(pkrtz(acc[mt][nt][r], acc[mt][nt][r + 1]));
          }
        }
      }
    }
  } else {
    unsigned char* kbase = lds + KS_OFF + buf * 9792;
#pragma unroll
    for (int mt = 0; mt < 3; ++mt) {
#pragma unroll
      for (int nt = 0; nt < 4; ++nt) {
        int d = nt * 16 + l15;
#pragma unroll
        for (int r = 0; r < 4; ++r) {
          int mrow = mt * 16 + lhi * 4 + r;
          if (mrow < 34) {
            int bbw = mrow >= 17 ? 1 : 0;
            int m = mrow - 17 * bbw;
            *(f16*)(kbase + (hhw * 2 + bbw) * 2448 + m * 144 + d * 2) = (f16)acc[mt][nt][r];
          }
        }
      }
    }
  }
}

__global__ __launch_bounds__(256, 2) void fused_k(
    const float* __restrict__ x, const float* __restrict__ n_g,
    const float* __restrict__ n_b, const f16* __restrict__ Wcat2,
    const float* __restrict__ bcat, const f16* __restrict__ q16h,
    float* __restrict__ out) {
  __shared__ __align__(16) unsigned char lds[LDS_TOTAL];
  const int b0 = blockIdx.x * 2;
  const int tid = threadIdx.x, wv = tid >> 6, lane = tid & 63;
  const int l15 = lane & 15, lhi = lane >> 4;
  const int chunk = l15 * 4 + lhi;

  // zero VT (both buffers + slack)
  {
    uint4 z;
    z.x = z.y = z.z = z.w = 0u;
    for (int i = tid; i < 1540; i += 256)
      *reinterpret_cast<uint4*>(lds + VT_OFF + i * 16) = z;
  }

  // Phase 1: LayerNorm -> xn f16 rows 0..33 (swizzled)
  for (int rr = wv; rr < 34; rr += 4) {
    const f32x4* xr = (const f32x4*)(x + ((size_t)(b0 * 17 + rr)) * D);
    f32x4 va = xr[lane * 2], vb = xr[lane * 2 + 1];
    float s = va[0] + va[1] + va[2] + va[3] + vb[0] + vb[1] + vb[2] + vb[3];
    float sq = va[0] * va[0] + va[1] * va[1] + va[2] * va[2] + va[3] * va[3] +
               vb[0] * vb[0] + vb[1] * vb[1] + vb[2] * vb[2] + vb[3] * vb[3];
#pragma unroll
    for (int off = 32; off; off >>= 1) {
      s += __shfl_xor(s, off);
      sq += __shfl_xor(sq, off);
    }
    float mu = s * (1.0f / 512.0f);
    float var = sq * (1.0f / 512.0f) - mu * mu;
    float rstd = rsqrtf(var + 1e-5f);
    f32x4 ga = ((const f32x4*)n_g)[lane * 2], gb = ((const f32x4*)n_g)[lane * 2 + 1];
    f32x4 ba = ((const f32x4*)n_b)[lane * 2], bb = ((const f32x4*)n_b)[lane * 2 + 1];
    uint4 u;
    u.x = bcu(pkrtz((va[0] - mu) * rstd * ga[0] + ba[0], (va[1] - mu) * rstd * ga[1] + ba[1]));
    u.y = bcu(pkrtz((va[2] - mu) * rstd * ga[2] + ba[2], (va[3] - mu) * rstd * ga[3] + ba[3]));
    u.z = bcu(pkrtz((vb[0] - mu) * rstd * gb[0] + bb[0], (vb[1] - mu) * rstd * gb[1] + bb[1]));
    u.w = bcu(pkrtz((vb[2] - mu) * rstd * gb[2] + bb[2], (vb[3] - mu) * rstd * gb[3] + bb[3]));
    *reinterpret_cast<uint4*>(lds + XN_OFF + rr * 1024 + ((lane * 16) ^ ((rr & 7) << 4))) = u;
  }
  __syncthreads();

  const int hhw = wv >> 1, isv = wv & 1;  // projection role (cols)
  const int bb = wv & 1;                  // attention combo = wv
  const int b = b0 + bb, bs = b & 15;
  const float C2 = 0.18033688011112042f;  // log2(e)/8

  // prologue: project head-pair 0 into buffer 0
  do_proj(Wcat2, bcat, lds, 0, 0, wv, l15, lhi, hhw, isv, chunk);
  __syncthreads();

  for (int hp = 0; hp < 4; ++hp) {
    const int buf = hp & 1;
    const int head_a = hp * 2 + hhw;

    // ---- project NEXT head-pair first (latency drains under attn) ----
    if (hp < 3)
      do_proj(Wcat2, bcat, lds, hp + 1, buf ^ 1, wv, l15, lhi, hhw, isv, chunk);

    // ---- attention: combo = wv ----
    const f16* qb = q16h + ((size_t)(head_a * 16 + bs) * 77) * 64;
    f16x8 qf[5][2];
#pragma unroll
    for (int nt = 0; nt < 5; ++nt) {
      int nq = nt * 16 + l15;
      if (nq > 76) nq = 76;
      qf[nt][0] = *(const f16x8*)(qb + nq * 64 + lhi * 8);
      qf[nt][1] = *(const f16x8*)(qb + nq * 64 + 32 + lhi * 8);
    }
    const unsigned char* ksb = lds + KS_OFF + buf * 9792 + wv * 2448;
    const unsigned char* vtb = lds + VT_OFF + buf * 12288 + wv * 3072;
    f16x8 kf0[2], kf1[2], vf[4];
#pragma unroll
    for (int c = 0; c < 2; ++c) {
      kf0[c] = *(const f16x8*)(ksb + l15 * 144 + c * 64 + lhi * 16);
      kf1[c] = *(const f16x8*)(ksb + 16 * 144 + c * 64 + lhi * 16);
    }
#pragma unroll
    for (int dt = 0; dt < 4; ++dt)
      vf[dt] = *(const f16x8*)(vtb + (dt * 16 + l15) * 48 + lhi * 16);

    float* ob = out + (size_t)b * 77 * 512 + head_a * 64;
#pragma unroll
    for (int nt = 0; nt < 5; ++nt) {
      f32x4 z = {0.f, 0.f, 0.f, 0.f};
      f32x4 s0 = z, s1 = z;
      s0 = __builtin_amdgcn_mfma_f32_16x16x32_f16(kf0[0], qf[nt][0], s0, 0, 0, 0);
      s0 = __builtin_amdgcn_mfma_f32_16x16x32_f16(kf0[1], qf[nt][1], s0, 0, 0, 0);
      s1 = __builtin_amdgcn_mfma_f32_16x16x32_f16(kf1[0], qf[nt][0], s1, 0, 0, 0);
      s1 = __builtin_amdgcn_mfma_f32_16x16x32_f16(kf1[1], qf[nt][1], s1, 0, 0, 0);
      float mx = fmaxf(fmaxf(s0[0], s0[1]), fmaxf(s0[2], s0[3]));
      mx = fmaxf(mx, __shfl_xor(mx, 16));
      mx = fmaxf(mx, __shfl_xor(mx, 32));
      mx = fmaxf(mx, s1[0]);
      float e0[4];
#pragma unroll
      for (int r = 0; r < 4; ++r) e0[r] = exp2f((s0[r] - mx) * C2);
      float e1 = exp2f((s1[0] - mx) * C2);
      float sm = e0[0] + e0[1] + e0[2] + e0[3];
      sm += __shfl_xor(sm, 16);
      sm += __shfl_xor(sm, 32);
      sm += e1;
      float inv = fastrcp(sm);
#pragma unroll
      for (int r = 0; r < 4; ++r) e0[r] *= inv;
      e1 *= inv;
      f16x8 pfrag = repack_frag(e0[0], e0[1], e0[2], e0[3], (lhi == 0) ? e1 : 0.f, l15, lhi);
#pragma unroll
      for (int dt = 0; dt < 4; ++dt) {
        f32x4 o = {0.f, 0.f, 0.f, 0.f};
        o = __builtin_amdgcn_mfma_f32_16x16x32_f16(pfrag, vf[dt], o, 0, 0, 0);
#pragma unroll
        for (int r = 0; r < 4; ++r) {
          int n = nt * 16 + lhi * 4 + r;
          if (n < 77) ob[(size_t)n * 512 + dt * 16 + l15] = o[r];
        }
      }
    }

    if (hp < 3) __syncthreads();
  }
}

extern "C" void kernel_launch(void* const* d_in, const int* in_sizes, int n_in,
                              void* d_out, int out_size, void* d_ws, size_t ws_size,
                              hipStream_t stream) {
  const float* xf = (const float*)d_in[0];
  const float* x = (const float*)d_in[1];
  const float* tn_g = (const float*)d_in[2];
  const float* tn_b = (const float*)d_in[3];
  const float* n_g = (const float*)d_in[4];
  const float* n_b = (const float*)d_in[5];
  const float* Wq = (const float*)d_in[6];
  const float* bq = (const float*)d_in[7];
  const float* Wk = (const float*)d_in[8];
  const float* bk = (const float*)d_in[9];
  const float* Wv = (const float*)d_in[10];
  const float* bv = (const float*)d_in[11];
  float* out = (float*)d_out;

  char* ws = (char*)d_ws;
  f16* q16h = (f16*)ws;                      // 8*16*77*64*2 = 1,261,568 B (+1024 pad)
  f16* Wcat2 = (f16*)(ws + 1262592);         // 16*32768*2   = 1,048,576 B
  float* bcat = (float*)(ws + 2311168);      // 1024*4       = 4,096 B

  prep_q_k<<<416, 256, 0, stream>>>(xf, tn_g, tn_b, Wq, bq, Wk, bk, Wv, bv,
                                    Wcat2, bcat, q16h);
  fused_k<<<1944, 256, 0, stream>>>(x, n_g, n_b, Wcat2, bcat, q16h, out);
}

// Round 19
// 279.546 us; speedup vs baseline: 2.9108x; 1.0400x over previous
//
#include <hip/hip_runtime.h>
#include <stdint.h>

#define D 512

typedef _Float16 f16;
typedef f16 f16x8 __attribute__((ext_vector_type(8)));
typedef f16 h2 __attribute__((ext_vector_type(2)));
typedef float f32x4 __attribute__((ext_vector_type(4)));
typedef unsigned int u32;
typedef u32 u32x4 __attribute__((ext_vector_type(4)));

static __device__ __forceinline__ u32 bcu(h2 h) { return __builtin_bit_cast(u32, h); }
static __device__ __forceinline__ h2 pkrtz(float a, float b) {
  return __builtin_bit_cast(h2, __builtin_amdgcn_cvt_pkrtz(a, b));
}
static __device__ __forceinline__ f16x8 frag4(u32 w0, u32 w1, u32 w2, u32 w3) {
  u32x4 u = {w0, w1, w2, w3};
  return __builtin_bit_cast(f16x8, u);
}
static __device__ __forceinline__ float fastrcp(float x) {
#if __has_builtin(__builtin_amdgcn_rcpf)
  return __builtin_amdgcn_rcpf(x);
#else
  return 1.0f / x;
#endif
}

// lhi-repack (verified R5-R18): C-layout tile pair -> A-frag (k=m, m 17..31 = 0).
static __device__ __forceinline__ f16x8 repack_frag(float c0, float c1, float c2, float c3,
                                                    float v16, int l15, int lhi) {
  u32 t0a = bcu(pkrtz(c0, c1)), t0b = bcu(pkrtz(c2, c3));
  u32 t1a = bcu(pkrtz(v16, 0.f));
  int srcA = (((lhi * 2) & 3) << 4) | l15;
  int srcB = (((lhi * 2 + 1) & 3) << 4) | l15;
  u32 a0 = (u32)__shfl((int)t0a, srcA);
  u32 a1 = (u32)__shfl((int)t0b, srcA);
  u32 a2 = (u32)__shfl((int)t1a, srcA);
  u32 b0 = (u32)__shfl((int)t0a, srcB);
  u32 b1 = (u32)__shfl((int)t0b, srcB);
  u32 b2 = (u32)__shfl((int)t1a, srcB);
  bool lo = lhi < 2;
  return frag4(lo ? a0 : a2, lo ? a1 : 0u, lo ? b0 : b2, lo ? b1 : 0u);
}

// ---------------- prep_q: blocks 0..255 = Wcat2 swizzle; 256..415 = qproj ----------------
// Wcat2: [slab][ks][nt][chunk] 16B chunks, chunk = l15*4+lhi (verified R18, coalesced).
// q16s:  [head][bs][f = nt*2+c][chunk = l15*4+lhi] 16B chunks:
//        data = q[n = nt*16+l15 (row 76 duplicated for 77..79)][c*32 + lhi*8 .. +8].
__global__ __launch_bounds__(256) void prep_q_k(
    const float* __restrict__ xf, const float* __restrict__ tn_g,
    const float* __restrict__ tn_b, const float* __restrict__ Wq,
    const float* __restrict__ bq, const float* __restrict__ Wk,
    const float* __restrict__ bk, const float* __restrict__ Wv,
    const float* __restrict__ bv, f16* __restrict__ Wcat2,
    float* __restrict__ bcat, f16* __restrict__ q16s) {
  __shared__ __align__(16) unsigned char lds[16384];
  const int bid = blockIdx.x, tid = threadIdx.x;
  const int wv = tid >> 6, lane = tid & 63;
  if (bid < 256) {
    const int s = bid >> 4, ks = bid & 15;
    const int nt = tid >> 6;
    const int cl = tid & 63;
    const int l15 = cl >> 2, lhi = cl & 3;
    int c = s * 64 + nt * 16 + l15;
    int h = c >> 7, kv = (c >> 6) & 1, d = c & 63;
    const float* src = (kv ? Wv : Wk) + (size_t)(h * 64 + d) * D + ks * 32 + lhi * 8;
    f32x4 a = *(const f32x4*)src;
    f32x4 cc = *(const f32x4*)(src + 4);
    uint4 out16;
    out16.x = bcu(pkrtz(a[0], a[1]));
    out16.y = bcu(pkrtz(a[2], a[3]));
    out16.z = bcu(pkrtz(cc[0], cc[1]));
    out16.w = bcu(pkrtz(cc[2], cc[3]));
    *reinterpret_cast<uint4*>(Wcat2 + ((size_t)((s * 16 + ks) * 4 + nt) * 64 + cl) * 8) = out16;
    if (ks == 0 && lhi == 0) bcat[c] = (kv ? bv : bk)[h * 64 + d];
    return;
  }
  // ---- qproj -> q16s fragment layout ----
  const int bid2 = bid - 256;          // 0..159
  const int bs = bid2 & 15;
  const int g = bid2 >> 4;             // 0..9
  const int n0 = (g >> 1) * 16;
  const int ch = g & 1;
  const int l15 = lane & 15, lhi = lane >> 4;

  for (int rr = wv; rr < 16; rr += 4) {
    int srcn = n0 + rr;
    if (srcn > 76) srcn = 76;
    const f32x4* xr = (const f32x4*)(xf + ((size_t)(bs * 77 + srcn)) * D);
    f32x4 va = xr[lane * 2], vb = xr[lane * 2 + 1];
    float s = va[0] + va[1] + va[2] + va[3] + vb[0] + vb[1] + vb[2] + vb[3];
    float sq = va[0] * va[0] + va[1] * va[1] + va[2] * va[2] + va[3] * va[3] +
               vb[0] * vb[0] + vb[1] * vb[1] + vb[2] * vb[2] + vb[3] * vb[3];
#pragma unroll
    for (int off = 32; off; off >>= 1) {
      s += __shfl_xor(s, off);
      sq += __shfl_xor(sq, off);
    }
    float mu = s * (1.0f / 512.0f);
    float var = sq * (1.0f / 512.0f) - mu * mu;
    float rstd = rsqrtf(var + 1e-5f);
    f32x4 ga = ((const f32x4*)tn_g)[lane * 2], gb = ((const f32x4*)tn_g)[lane * 2 + 1];
    f32x4 ba = ((const f32x4*)tn_b)[lane * 2], bb = ((const f32x4*)tn_b)[lane * 2 + 1];
    uint4 u;
    u.x = bcu(pkrtz((va[0] - mu) * rstd * ga[0] + ba[0], (va[1] - mu) * rstd * ga[1] + ba[1]));
    u.y = bcu(pkrtz((va[2] - mu) * rstd * ga[2] + ba[2], (va[3] - mu) * rstd * ga[3] + ba[3]));
    u.z = bcu(pkrtz((vb[0] - mu) * rstd * gb[0] + bb[0], (vb[1] - mu) * rstd * gb[1] + bb[1]));
    u.w = bcu(pkrtz((vb[2] - mu) * rstd * gb[2] + bb[2], (vb[3] - mu) * rstd * gb[3] + bb[3]));
    *reinterpret_cast<uint4*>(lds + rr * 1024 + ((lane * 16) ^ ((rr & 7) << 4))) = u;
  }
  __syncthreads();

  f32x4 acc[4];
#pragma unroll
  for (int nt = 0; nt < 4; ++nt) {
    float bias = bq[ch * 256 + wv * 64 + nt * 16 + l15];
    acc[nt] = (f32x4){bias, bias, bias, bias};
  }
#pragma unroll 4
  for (int ks = 0; ks < 16; ++ks) {
    f16x8 af = *(const f16x8*)(lds + l15 * 1024 + ((ks * 64 + lhi * 16) ^ ((l15 & 7) << 4)));
#pragma unroll
    for (int nt = 0; nt < 4; ++nt) {
      const float* wr = Wq + (size_t)(ch * 256 + wv * 64 + nt * 16 + l15) * D + ks * 32 + lhi * 8;
      f32x4 wa = *(const f32x4*)wr, wb = *(const f32x4*)(wr + 4);
      f16x8 bf = frag4(bcu(pkrtz(wa[0], wa[1])), bcu(pkrtz(wa[2], wa[3])),
                       bcu(pkrtz(wb[0], wb[1])), bcu(pkrtz(wb[2], wb[3])));
      acc[nt] = __builtin_amdgcn_mfma_f32_16x16x32_f16(af, bf, acc[nt], 0, 0, 0);
    }
  }
  // write fragment-ordered q16s
#pragma unroll
  for (int nt = 0; nt < 4; ++nt) {
    int col = ch * 256 + wv * 64 + nt * 16 + l15;
    int h = col >> 6, dcol = col & 63;
    int c = dcol >> 5, lhiq = (dcol >> 3) & 3, j = dcol & 7;
    f16* base = q16s + (size_t)(h * 16 + bs) * 5120;  // 10 frags * 512
#pragma unroll
    for (int r = 0; r < 4; ++r) {
      int n = n0 + lhi * 4 + r;
      if (n < 77) {
        int ntq = n >> 4, l15q = n & 15;
        f16 val = (f16)acc[nt][r];
        base[(ntq * 2 + c) * 512 + (l15q * 4 + lhiq) * 8 + j] = val;
        if (n == 76) {
#pragma unroll
          for (int dup = 13; dup <= 15; ++dup)
            base[(4 * 2 + c) * 512 + (dup * 4 + lhiq) * 8 + j] = val;
        }
      }
    }
  }
}

// ---------------- fused (R19 = R18 + coalesced fragment-ordered q loads) ----------------
#define XN_OFF 0
#define KS_OFF 34816
#define VT_OFF 54400
#define LDS_TOTAL 79040

static __device__ __forceinline__ void do_proj(
    const f16* __restrict__ Wcat2, const float* __restrict__ bcat,
    unsigned char* lds, int hp, int buf, int wv, int l15, int lhi, int hhw, int isv,
    int chunk) {
  f32x4 acc[3][4];
#pragma unroll
  for (int nt = 0; nt < 4; ++nt) {
    float bias = bcat[hp * 256 + wv * 64 + nt * 16 + l15];
    f32x4 bi = {bias, bias, bias, bias};
#pragma unroll
    for (int mt = 0; mt < 3; ++mt) acc[mt][nt] = bi;
  }
  const f16* wbase = Wcat2 + (size_t)(hp * 4 + wv) * 32768;
  f16x8 bf[3][4];
#pragma unroll
  for (int p = 0; p < 3; ++p)
#pragma unroll
    for (int nt = 0; nt < 4; ++nt)
      bf[p][nt] = *(const f16x8*)(wbase + ((p * 4 + nt) * 64 + chunk) * 8);
#pragma unroll
  for (int ks = 0; ks < 16; ++ks) {
    const int cur = ks % 3;
#pragma unroll
    for (int mt = 0; mt < 3; ++mt) {
      int arow = mt * 16 + l15;
      f16x8 af = *(const f16x8*)(lds + XN_OFF + arow * 1024 +
                                 ((ks * 64 + lhi * 16) ^ ((arow & 7) << 4)));
#pragma unroll
      for (int nt = 0; nt < 4; ++nt)
        acc[mt][nt] =
            __builtin_amdgcn_mfma_f32_16x16x32_f16(af, bf[cur][nt], acc[mt][nt], 0, 0, 0);
    }
    if (ks < 13) {
#pragma unroll
      for (int nt = 0; nt < 4; ++nt)
        bf[cur][nt] = *(const f16x8*)(wbase + (((ks + 3) * 4 + nt) * 64 + chunk) * 8);
    }
  }
  if (isv) {
    unsigned char* vbase = lds + VT_OFF + buf * 12288;
#pragma unroll
    for (int mt = 0; mt < 3; ++mt) {
#pragma unroll
      for (int nt = 0; nt < 4; ++nt) {
        int d = nt * 16 + l15;
#pragma unroll
        for (int r = 0; r < 4; r += 2) {
          int mrow = mt * 16 + lhi * 4 + r;  // even
          if (mrow == 16) {
            *(f16*)(vbase + (hhw * 2 + 0) * 3072 + d * 48 + 16 * 2) = (f16)acc[mt][nt][r];
            *(f16*)(vbase + (hhw * 2 + 1) * 3072 + d * 48 + 0) = (f16)acc[mt][nt][r + 1];
          } else if (mrow < 34) {
            int bbw = mrow >= 17 ? 1 : 0;
            int m = mrow - 17 * bbw;
            *(u32*)(vbase + (hhw * 2 + bbw) * 3072 + d * 48 + m * 2) =
                bcu(pkrtz(acc[mt][nt][r], acc[mt][nt][r + 1]));
          }
        }
      }
    }
  } else {
    unsigned char* kbase = lds + KS_OFF + buf * 9792;
#pragma unroll
    for (int mt = 0; mt < 3; ++mt) {
#pragma unroll
      for (int nt = 0; nt < 4; ++nt) {
        int d = nt * 16 + l15;
#pragma unroll
        for (int r = 0; r < 4; ++r) {
          int mrow = mt * 16 + lhi * 4 + r;
          if (mrow < 34) {
            int bbw = mrow >= 17 ? 1 : 0;
            int m = mrow - 17 * bbw;
            *(f16*)(kbase + (hhw * 2 + bbw) * 2448 + m * 144 + d * 2) = (f16)acc[mt][nt][r];
          }
        }
      }
    }
  }
}

__global__ __launch_bounds__(256, 2) void fused_k(
    const float* __restrict__ x, const float* __restrict__ n_g,
    const float* __restrict__ n_b, const f16* __restrict__ Wcat2,
    const float* __restrict__ bcat, const f16* __restrict__ q16s,
    float* __restrict__ out) {
  __shared__ __align__(16) unsigned char lds[LDS_TOTAL];
  const int b0 = blockIdx.x * 2;
  const int tid = threadIdx.x, wv = tid >> 6, lane = tid & 63;
  const int l15 = lane & 15, lhi = lane >> 4;
  const int chunk = l15 * 4 + lhi;

  // zero VT (both buffers + slack)
  {
    uint4 z;
    z.x = z.y = z.z = z.w = 0u;
    for (int i = tid; i < 1540; i += 256)
      *reinterpret_cast<uint4*>(lds + VT_OFF + i * 16) = z;
  }

  // Phase 1: LayerNorm -> xn f16 rows 0..33 (swizzled)
  for (int rr = wv; rr < 34; rr += 4) {
    const f32x4* xr = (const f32x4*)(x + ((size_t)(b0 * 17 + rr)) * D);
    f32x4 va = xr[lane * 2], vb = xr[lane * 2 + 1];
    float s = va[0] + va[1] + va[2] + va[3] + vb[0] + vb[1] + vb[2] + vb[3];
    float sq = va[0] * va[0] + va[1] * va[1] + va[2] * va[2] + va[3] * va[3] +
               vb[0] * vb[0] + vb[1] * vb[1] + vb[2] * vb[2] + vb[3] * vb[3];
#pragma unroll
    for (int off = 32; off; off >>= 1) {
      s += __shfl_xor(s, off);
      sq += __shfl_xor(sq, off);
    }
    float mu = s * (1.0f / 512.0f);
    float var = sq * (1.0f / 512.0f) - mu * mu;
    float rstd = rsqrtf(var + 1e-5f);
    f32x4 ga = ((const f32x4*)n_g)[lane * 2], gb = ((const f32x4*)n_g)[lane * 2 + 1];
    f32x4 ba = ((const f32x4*)n_b)[lane * 2], bb = ((const f32x4*)n_b)[lane * 2 + 1];
    uint4 u;
    u.x = bcu(pkrtz((va[0] - mu) * rstd * ga[0] + ba[0], (va[1] - mu) * rstd * ga[1] + ba[1]));
    u.y = bcu(pkrtz((va[2] - mu) * rstd * ga[2] + ba[2], (va[3] - mu) * rstd * ga[3] + ba[3]));
    u.z = bcu(pkrtz((vb[0] - mu) * rstd * gb[0] + bb[0], (vb[1] - mu) * rstd * gb[1] + bb[1]));
    u.w = bcu(pkrtz((vb[2] - mu) * rstd * gb[2] + bb[2], (vb[3] - mu) * rstd * gb[3] + bb[3]));
    *reinterpret_cast<uint4*>(lds + XN_OFF + rr * 1024 + ((lane * 16) ^ ((rr & 7) << 4))) = u;
  }
  __syncthreads();

  const int hhw = wv >> 1, isv = wv & 1;  // projection role (cols)
  const int bb = wv & 1;                  // attention combo = wv
  const int b = b0 + bb, bs = b & 15;
  const float C2 = 0.18033688011112042f;  // log2(e)/8

  // prologue: project head-pair 0 into buffer 0
  do_proj(Wcat2, bcat, lds, 0, 0, wv, l15, lhi, hhw, isv, chunk);
  __syncthreads();

  for (int hp = 0; hp < 4; ++hp) {
    const int buf = hp & 1;
    const int head_a = hp * 2 + hhw;

    // ---- project NEXT head-pair first (latency drains under attn) ----
    if (hp < 3)
      do_proj(Wcat2, bcat, lds, hp + 1, buf ^ 1, wv, l15, lhi, hhw, isv, chunk);

    // ---- attention: combo = wv; q loads fully coalesced from q16s ----
    const f16* qb = q16s + (size_t)(head_a * 16 + bs) * 5120;
    f16x8 qf[5][2];
#pragma unroll
    for (int nt = 0; nt < 5; ++nt) {
      qf[nt][0] = *(const f16x8*)(qb + (nt * 2 + 0) * 512 + chunk * 8);
      qf[nt][1] = *(const f16x8*)(qb + (nt * 2 + 1) * 512 + chunk * 8);
    }
    const unsigned char* ksb = lds + KS_OFF + buf * 9792 + wv * 2448;
    const unsigned char* vtb = lds + VT_OFF + buf * 12288 + wv * 3072;
    f16x8 kf0[2], kf1[2], vf[4];
#pragma unroll
    for (int c = 0; c < 2; ++c) {
      kf0[c] = *(const f16x8*)(ksb + l15 * 144 + c * 64 + lhi * 16);
      kf1[c] = *(const f16x8*)(ksb + 16 * 144 + c * 64 + lhi * 16);
    }
#pragma unroll
    for (int dt = 0; dt < 4; ++dt)
      vf[dt] = *(const f16x8*)(vtb + (dt * 16 + l15) * 48 + lhi * 16);

    float* ob = out + (size_t)b * 77 * 512 + head_a * 64;
#pragma unroll
    for (int nt = 0; nt < 5; ++nt) {
      f32x4 z = {0.f, 0.f, 0.f, 0.f};
      f32x4 s0 = z, s1 = z;
      s0 = __builtin_amdgcn_mfma_f32_16x16x32_f16(kf0[0], qf[nt][0], s0, 0, 0, 0);
      s0 = __builtin_amdgcn_mfma_f32_16x16x32_f16(kf0[1], qf[nt][1], s0, 0, 0, 0);
      s1 = __builtin_amdgcn_mfma_f32_16x16x32_f16(kf1[0], qf[nt][0], s1, 0, 0, 0);
      s1 = __builtin_amdgcn_mfma_f32_16x16x32_f16(kf1[1], qf[nt][1], s1, 0, 0, 0);
      float mx = fmaxf(fmaxf(s0[0], s0[1]), fmaxf(s0[2], s0[3]));
      mx = fmaxf(mx, __shfl_xor(mx, 16));
      mx = fmaxf(mx, __shfl_xor(mx, 32));
      mx = fmaxf(mx, s1[0]);
      float e0[4];
#pragma unroll
      for (int r = 0; r < 4; ++r) e0[r] = exp2f((s0[r] - mx) * C2);
      float e1 = exp2f((s1[0] - mx) * C2);
      float sm = e0[0] + e0[1] + e0[2] + e0[3];
      sm += __shfl_xor(sm, 16);
      sm += __shfl_xor(sm, 32);
      sm += e1;
      float inv = fastrcp(sm);
#pragma unroll
      for (int r = 0; r < 4; ++r) e0[r] *= inv;
      e1 *= inv;
      f16x8 pfrag = repack_frag(e0[0], e0[1], e0[2], e0[3], (lhi == 0) ? e1 : 0.f, l15, lhi);
#pragma unroll
      for (int dt = 0; dt < 4; ++dt) {
        f32x4 o = {0.f, 0.f, 0.f, 0.f};
        o = __builtin_amdgcn_mfma_f32_16x16x32_f16(pfrag, vf[dt], o, 0, 0, 0);
#pragma unroll
        for (int r = 0; r < 4; ++r) {
          int n = nt * 16 + lhi * 4 + r;
          if (n < 77) ob[(size_t)n * 512 + dt * 16 + l15] = o[r];
        }
      }
    }

    if (hp < 3) __syncthreads();
  }
}

extern "C" void kernel_launch(void* const* d_in, const int* in_sizes, int n_in,
                              void* d_out, int out_size, void* d_ws, size_t ws_size,
                              hipStream_t stream) {
  const float* xf = (const float*)d_in[0];
  const float* x = (const float*)d_in[1];
  const float* tn_g = (const float*)d_in[2];
  const float* tn_b = (const float*)d_in[3];
  const float* n_g = (const float*)d_in[4];
  const float* n_b = (const float*)d_in[5];
  const float* Wq = (const float*)d_in[6];
  const float* bq = (const float*)d_in[7];
  const float* Wk = (const float*)d_in[8];
  const float* bk = (const float*)d_in[9];
  const float* Wv = (const float*)d_in[10];
  const float* bv = (const float*)d_in[11];
  float* out = (float*)d_out;

  char* ws = (char*)d_ws;
  f16* q16s = (f16*)ws;                      // 8*16*10*512*2 = 1,310,720 B
  f16* Wcat2 = (f16*)(ws + 1310720);         // 16*32768*2    = 1,048,576 B
  float* bcat = (float*)(ws + 2359296);      // 1024*4        = 4,096 B

  prep_q_k<<<416, 256, 0, stream>>>(xf, tn_g, tn_b, Wq, bq, Wk, bk, Wv, bv,
                                    Wcat2, bcat, q16s);
  fused_k<<<1944, 256, 0, stream>>>(x, n_g, n_b, Wcat2, bcat, q16s, out);
}